// Round 2
// baseline (892.779 us; speedup 1.0000x reference)
//
#include <hip/hip_runtime.h>
#include <hip/hip_bf16.h>
#include <stdint.h>

// CrossAttention forward, MI355X/gfx950.
// Pipeline: f32->bf16 convert, W transposes, 3x proj GEMM (MFMA bf16),
// flash attention, output GEMM + bias (f32 out).
// Workspace layout (needs >= 88 MB):
//   [0,16)MB   Xb      bf16 [8192][1024]
//   [16,18)    WqT     bf16 [1024][1024]  (N-major: Wt[n][k])
//   [18,20)    WkT
//   [20,22)    WvT
//   [22,24)    WoT
//   [24,40)    Qb      bf16 [B=4][H=16][S=2048][d=64]
//   [40,56)    Kb      bf16 [4][16][2048][64]
//   [56,72)    Vt      bf16 [4][16][64][2048]   (transposed for PV B-frags)
//   [72,88)    Ab      bf16 [8192][1024]        (attention out, head-merged)

typedef unsigned short u16;
typedef __attribute__((ext_vector_type(8))) short short8;   // 8 x bf16
typedef __attribute__((ext_vector_type(4))) float f32x4;
typedef __attribute__((ext_vector_type(4))) unsigned short us4;

#define AS1 __attribute__((address_space(1)))
#define AS3 __attribute__((address_space(3)))

__device__ __forceinline__ u16 f2bf(float x) {
    union { float f; uint32_t u; } c; c.f = x;
    uint32_t r = c.u + 0x7fffu + ((c.u >> 16) & 1u);   // RNE
    return (u16)(r >> 16);
}

__device__ __forceinline__ float bf2f(u16 x) {
    union { uint32_t u; float f; } c; c.u = (uint32_t)x << 16;
    return c.f;
}

__device__ __forceinline__ short8 ld8(const u16* p) { return *(const short8*)p; }

__device__ __forceinline__ void gld_lds16(const u16* g, u16* l) {
    __builtin_amdgcn_global_load_lds((const AS1 void*)g, (AS3 void*)l, 16, 0, 0);
}

// ---------------- convert f32 -> bf16 (vectorized x4) ----------------
__global__ void k_convert(const float* __restrict__ in, u16* __restrict__ out, int n4) {
    int i = blockIdx.x * blockDim.x + threadIdx.x;
    if (i >= n4) return;
    float4 v = *((const float4*)in + i);
    us4 o = { f2bf(v.x), f2bf(v.y), f2bf(v.z), f2bf(v.w) };
    *((us4*)out + i) = o;
}

// ---------------- transpose 4 weights, f32[K][N] -> bf16[N][K] ----------------
__global__ void k_transpose4(const float* __restrict__ W0, const float* __restrict__ W1,
                             const float* __restrict__ W2, const float* __restrict__ W3,
                             u16* __restrict__ T0, u16* __restrict__ T1,
                             u16* __restrict__ T2, u16* __restrict__ T3) {
    const float* W; u16* T;
    switch (blockIdx.z) {
        case 0: W = W0; T = T0; break;
        case 1: W = W1; T = T1; break;
        case 2: W = W2; T = T2; break;
        default: W = W3; T = T3; break;
    }
    __shared__ float tile[32][33];
    int n0 = blockIdx.x * 32, k0 = blockIdx.y * 32;
    int tx = threadIdx.x, ty = threadIdx.y;   // block (32,8)
    #pragma unroll
    for (int j = 0; j < 32; j += 8)
        tile[ty + j][tx] = W[(size_t)(k0 + ty + j) * 1024 + n0 + tx];
    __syncthreads();
    #pragma unroll
    for (int j = 0; j < 32; j += 8)
        T[(size_t)(n0 + ty + j) * 1024 + k0 + tx] = f2bf(tile[tx][ty + j]);
}

// ---------------- GEMM: C[8192x1024] = A[8192x1024] * Bt[1024x1024]^T ----------------
// MODE 0: bf16 out in [B,H,S,d] layout    (Q, K projections)
// MODE 1: bf16 out in [B,H,d,S] layout    (V projection, transposed)
// MODE 2: f32 out row-major + bias        (final output GEMM)
template<int MODE>
__global__ __launch_bounds__(256)
void k_gemm(const u16* __restrict__ A, const u16* __restrict__ Bt,
            u16* __restrict__ outb, float* __restrict__ outf, const float* __restrict__ bias) {
    __shared__ u16 lA[128 * 64];
    __shared__ u16 lB[128 * 64];
    const int lane = threadIdx.x & 63, wave = threadIdx.x >> 6;
    const int lo = lane & 15, hi = lane >> 4;
    const int m0 = blockIdx.x * 128, n0 = blockIdx.y * 128;
    const int wr = wave >> 1, wc = wave & 1;     // wave -> 64x64 quadrant
    const int srow = lane >> 3;                  // staging row within 8-row chunk
    const int scol = (lane & 7) * 8;             // staging col (elements)

    f32x4 acc[4][4];
    #pragma unroll
    for (int mi = 0; mi < 4; mi++)
        #pragma unroll
        for (int ni = 0; ni < 4; ni++)
            acc[mi][ni] = f32x4{0.f, 0.f, 0.f, 0.f};

    for (int k0 = 0; k0 < 1024; k0 += 64) {
        __syncthreads();   // previous compute done before overwrite
        #pragma unroll
        for (int i = 0; i < 4; i++) {
            int c = i * 4 + wave;                // 16 chunks of 8 rows
            int r = c * 8 + srow;
            gld_lds16(A  + (size_t)(m0 + r) * 1024 + k0 + scol, lA + c * 512);
            gld_lds16(Bt + (size_t)(n0 + r) * 1024 + k0 + scol, lB + c * 512);
        }
        __syncthreads();   // drains vmcnt for global_load_lds
        #pragma unroll
        for (int kk = 0; kk < 2; kk++) {
            short8 af[4], bf[4];
            #pragma unroll
            for (int mi = 0; mi < 4; mi++)
                af[mi] = ld8(lA + (wr * 64 + mi * 16 + lo) * 64 + kk * 32 + hi * 8);
            #pragma unroll
            for (int ni = 0; ni < 4; ni++)
                bf[ni] = ld8(lB + (wc * 64 + ni * 16 + lo) * 64 + kk * 32 + hi * 8);
            #pragma unroll
            for (int mi = 0; mi < 4; mi++)
                #pragma unroll
                for (int ni = 0; ni < 4; ni++)
                    acc[mi][ni] = __builtin_amdgcn_mfma_f32_16x16x32_bf16(
                        af[mi], bf[ni], acc[mi][ni], 0, 0, 0);
        }
    }

    // epilogue: C frag mapping col=lane&15, row=(lane>>4)*4+reg (m89-verified)
    #pragma unroll
    for (int mi = 0; mi < 4; mi++) {
        #pragma unroll
        for (int ni = 0; ni < 4; ni++) {
            #pragma unroll
            for (int r = 0; r < 4; r++) {
                int row = m0 + wr * 64 + mi * 16 + hi * 4 + r;   // 0..8191
                int col = n0 + wc * 64 + ni * 16 + lo;           // 0..1023
                float v = acc[mi][ni][r];
                if (MODE == 2) {
                    outf[(size_t)row * 1024 + col] = v + bias[col];
                } else {
                    int b = row >> 11, s = row & 2047, h = col >> 6, dh = col & 63;
                    if (MODE == 0)
                        outb[((size_t)(b * 16 + h) * 2048 + s) * 64 + dh] = f2bf(v);
                    else
                        outb[((size_t)(b * 16 + h) * 64 + dh) * 2048 + s] = f2bf(v);
                }
            }
        }
    }
}

// ---------------- flash attention ----------------
// grid (S/128=16, B*H=64), block 256 (4 waves x 32 q-rows).
// K, Vt fragments read directly from global (L2-resident per head).
__global__ __launch_bounds__(256)
void k_attn(const u16* __restrict__ Q, const u16* __restrict__ K,
            const u16* __restrict__ Vt, u16* __restrict__ O) {
    const int lane = threadIdx.x & 63, wave = threadIdx.x >> 6;
    const int lo = lane & 15, hi = lane >> 4;
    const int qt = blockIdx.x, bh = blockIdx.y;
    const u16* q  = Q  + (size_t)bh * 2048 * 64;
    const u16* k  = K  + (size_t)bh * 2048 * 64;
    const u16* vt = Vt + (size_t)bh * 64 * 2048;

    __shared__ u16 Plds[4][32 * 64];    // per-wave P buffer, XOR-swizzled
    u16* pw = Plds[wave];

    const int q0 = qt * 128 + wave * 32;
    const float SL = 0.18033688011112042f;   // 0.125 * log2(e)

    // Q fragments, hoisted (A-frag: row=lane&15, k=(lane>>4)*8+j)
    short8 qf[2][2];
    #pragma unroll
    for (int s = 0; s < 2; s++)
        #pragma unroll
        for (int kk = 0; kk < 2; kk++)
            qf[s][kk] = ld8(q + (size_t)(q0 + s * 16 + lo) * 64 + kk * 32 + hi * 8);

    f32x4 acc[2][4];
    #pragma unroll
    for (int s = 0; s < 2; s++)
        #pragma unroll
        for (int dt = 0; dt < 4; dt++)
            acc[s][dt] = f32x4{0.f, 0.f, 0.f, 0.f};
    float m2[2][4], lden[2][4];
    #pragma unroll
    for (int s = 0; s < 2; s++)
        #pragma unroll
        for (int r = 0; r < 4; r++) { m2[s][r] = -1e30f; lden[s][r] = 0.f; }

    for (int kv0 = 0; kv0 < 2048; kv0 += 64) {
        // ---- S = Q K^T (raw, scale folded into exp2 below) ----
        f32x4 sc[2][4];
        #pragma unroll
        for (int s = 0; s < 2; s++)
            #pragma unroll
            for (int ct = 0; ct < 4; ct++)
                sc[s][ct] = f32x4{0.f, 0.f, 0.f, 0.f};
        #pragma unroll
        for (int ct = 0; ct < 4; ct++) {
            #pragma unroll
            for (int kk = 0; kk < 2; kk++) {
                short8 kf = ld8(k + (size_t)(kv0 + ct * 16 + lo) * 64 + kk * 32 + hi * 8);
                sc[0][ct] = __builtin_amdgcn_mfma_f32_16x16x32_bf16(qf[0][kk], kf, sc[0][ct], 0, 0, 0);
                sc[1][ct] = __builtin_amdgcn_mfma_f32_16x16x32_bf16(qf[1][kk], kf, sc[1][ct], 0, 0, 0);
            }
        }
        // ---- online softmax (log2 domain), rows live in (hi*4+r) ----
        float p[2][4][4];
        #pragma unroll
        for (int s = 0; s < 2; s++) {
            #pragma unroll
            for (int r = 0; r < 4; r++) {
                float mx = fmaxf(fmaxf(sc[s][0][r], sc[s][1][r]), fmaxf(sc[s][2][r], sc[s][3][r]));
                mx = fmaxf(mx, __shfl_xor(mx, 1));
                mx = fmaxf(mx, __shfl_xor(mx, 2));
                mx = fmaxf(mx, __shfl_xor(mx, 4));
                mx = fmaxf(mx, __shfl_xor(mx, 8));
                float mn = fmaxf(m2[s][r], mx * SL);
                float al = exp2f(m2[s][r] - mn);
                m2[s][r] = mn;
                float sum = 0.f;
                #pragma unroll
                for (int ct = 0; ct < 4; ct++) {
                    // round to bf16 FIRST so lden matches the bf16 P used in PV
                    float pv = bf2f(f2bf(exp2f(sc[s][ct][r] * SL - mn)));
                    p[s][ct][r] = pv;
                    sum += pv;
                }
                sum += __shfl_xor(sum, 1);
                sum += __shfl_xor(sum, 2);
                sum += __shfl_xor(sum, 4);
                sum += __shfl_xor(sum, 8);
                lden[s][r] = lden[s][r] * al + sum;
                // rescale ONLY row r of each accumulator (bug fix from R1:
                // previously multiplied the whole f32x4 per r -> al^4 applied)
                #pragma unroll
                for (int dt = 0; dt < 4; dt++) acc[s][dt][r] *= al;
            }
        }
        // ---- P -> LDS (bf16, pair-packed, XOR swizzle byte^=(row&7)<<4) ----
        #pragma unroll
        for (int s = 0; s < 2; s++) {
            #pragma unroll
            for (int ct = 0; ct < 4; ct++) {
                #pragma unroll
                for (int r = 0; r < 4; r++) {
                    float v0 = p[s][ct][r];
                    float v1 = __shfl_xor(v0, 1);
                    if (!(lane & 1)) {
                        int row = s * 16 + hi * 4 + r;
                        int byteoff = (row * 128 + (ct * 16 + lo) * 2) ^ ((row & 7) << 4);
                        *(uint32_t*)((char*)pw + byteoff) =
                            (uint32_t)f2bf(v0) | ((uint32_t)f2bf(v1) << 16);
                    }
                }
            }
        }
        // ---- O += P V  (A-frag from swizzled LDS, B-frag from Vt global) ----
        #pragma unroll
        for (int nb = 0; nb < 2; nb++) {
            short8 pa[2];
            #pragma unroll
            for (int s = 0; s < 2; s++) {
                int row = s * 16 + lo;
                int byteoff = (row * 128 + (nb * 32 + hi * 8) * 2) ^ ((row & 7) << 4);
                pa[s] = *(const short8*)((const char*)pw + byteoff);
            }
            #pragma unroll
            for (int dt = 0; dt < 4; dt++) {
                short8 vf = ld8(vt + (size_t)(dt * 16 + lo) * 2048 + kv0 + nb * 32 + hi * 8);
                acc[0][dt] = __builtin_amdgcn_mfma_f32_16x16x32_bf16(pa[0], vf, acc[0][dt], 0, 0, 0);
                acc[1][dt] = __builtin_amdgcn_mfma_f32_16x16x32_bf16(pa[1], vf, acc[1][dt], 0, 0, 0);
            }
        }
    }

    // ---- normalize + write [B,S,H*d] bf16 ----
    const int b = bh >> 4, h = bh & 15;
    #pragma unroll
    for (int s = 0; s < 2; s++) {
        #pragma unroll
        for (int dt = 0; dt < 4; dt++) {
            #pragma unroll
            for (int r = 0; r < 4; r++) {
                float o = acc[s][dt][r] / lden[s][r];
                int rowg = q0 + s * 16 + hi * 4 + r;
                int col  = dt * 16 + lo;
                O[((size_t)(b * 2048 + rowg)) * 1024 + h * 64 + col] = f2bf(o);
            }
        }
    }
}

// ---------------- launcher ----------------
extern "C" void kernel_launch(void* const* d_in, const int* in_sizes, int n_in,
                              void* d_out, int out_size, void* d_ws, size_t ws_size,
                              hipStream_t stream) {
    const float* X  = (const float*)d_in[0];
    const float* Wq = (const float*)d_in[1];
    const float* Wk = (const float*)d_in[2];
    const float* Wv = (const float*)d_in[3];
    const float* Wo = (const float*)d_in[4];
    const float* bo = (const float*)d_in[5];
    float* out = (float*)d_out;
    char* ws = (char*)d_ws;
    const size_t MB = 1024 * 1024;
    u16* Xb  = (u16*)(ws + 0 * MB);
    u16* WqT = (u16*)(ws + 16 * MB);
    u16* WkT = (u16*)(ws + 18 * MB);
    u16* WvT = (u16*)(ws + 20 * MB);
    u16* WoT = (u16*)(ws + 22 * MB);
    u16* Qb  = (u16*)(ws + 24 * MB);
    u16* Kb  = (u16*)(ws + 40 * MB);
    u16* Vt  = (u16*)(ws + 56 * MB);
    u16* Ab  = (u16*)(ws + 72 * MB);

    k_convert<<<8192, 256, 0, stream>>>(X, Xb, 8192 * 1024 / 4);
    k_transpose4<<<dim3(32, 32, 4), dim3(32, 8), 0, stream>>>(Wq, Wk, Wv, Wo, WqT, WkT, WvT, WoT);
    dim3 g(64, 8), blk(256);
    k_gemm<0><<<g, blk, 0, stream>>>(Xb, WqT, Qb, nullptr, nullptr);
    k_gemm<0><<<g, blk, 0, stream>>>(Xb, WkT, Kb, nullptr, nullptr);
    k_gemm<1><<<g, blk, 0, stream>>>(Xb, WvT, Vt, nullptr, nullptr);
    k_attn<<<dim3(16, 64), 256, 0, stream>>>(Qb, Kb, Vt, Ab);
    k_gemm<2><<<g, blk, 0, stream>>>(Ab, WoT, nullptr, out, bo);
}

// Round 3
// 838.859 us; speedup vs baseline: 1.0643x; 1.0643x over previous
//
#include <hip/hip_runtime.h>
#include <hip/hip_bf16.h>
#include <stdint.h>

// CrossAttention forward, MI355X/gfx950.
// Workspace layout (needs >= 88 MB): see R2. Unchanged except k_attn rewrite:
// 8-wave blocks, LDS-staged double-buffered K/V with XOR swizzle, DPP reduces.

typedef unsigned short u16;
typedef __attribute__((ext_vector_type(8))) short short8;   // 8 x bf16
typedef __attribute__((ext_vector_type(4))) float f32x4;
typedef __attribute__((ext_vector_type(4))) unsigned short us4;

#define AS1 __attribute__((address_space(1)))
#define AS3 __attribute__((address_space(3)))

#if __has_builtin(__builtin_amdgcn_exp2f)
#define EXP2(x) __builtin_amdgcn_exp2f(x)
#else
#define EXP2(x) exp2f(x)
#endif

// DPP cross-lane (VALU pipe, not LDS): ctrl must be a constant.
// 0xB1 = quad_perm[1,0,3,2] (xor1), 0x4E = quad_perm[2,3,0,1] (xor2),
// 0x124 = row_ror:4, 0x128 = row_ror:8  (row = 16 lanes = our `lo` group)
#define DPPF(x, ctrl) (__builtin_bit_cast(float, __builtin_amdgcn_update_dpp( \
    0, __builtin_bit_cast(int, (float)(x)), (ctrl), 0xf, 0xf, true)))
#define DPPU(x, ctrl) ((uint32_t)__builtin_amdgcn_update_dpp( \
    0, (int)(x), (ctrl), 0xf, 0xf, true))

__device__ __forceinline__ u16 f2bf(float x) {
    union { float f; uint32_t u; } c; c.f = x;
    uint32_t r = c.u + 0x7fffu + ((c.u >> 16) & 1u);   // RNE
    return (u16)(r >> 16);
}

__device__ __forceinline__ float bf2f(u16 x) {
    union { uint32_t u; float f; } c; c.u = (uint32_t)x << 16;
    return c.f;
}

__device__ __forceinline__ short8 ld8(const u16* p) { return *(const short8*)p; }

__device__ __forceinline__ void gld_lds16(const u16* g, u16* l) {
    __builtin_amdgcn_global_load_lds((const AS1 void*)g, (AS3 void*)l, 16, 0, 0);
}

// ---------------- convert f32 -> bf16 (vectorized x4) ----------------
__global__ void k_convert(const float* __restrict__ in, u16* __restrict__ out, int n4) {
    int i = blockIdx.x * blockDim.x + threadIdx.x;
    if (i >= n4) return;
    float4 v = *((const float4*)in + i);
    us4 o = { f2bf(v.x), f2bf(v.y), f2bf(v.z), f2bf(v.w) };
    *((us4*)out + i) = o;
}

// ---------------- transpose 4 weights, f32[K][N] -> bf16[N][K] ----------------
__global__ void k_transpose4(const float* __restrict__ W0, const float* __restrict__ W1,
                             const float* __restrict__ W2, const float* __restrict__ W3,
                             u16* __restrict__ T0, u16* __restrict__ T1,
                             u16* __restrict__ T2, u16* __restrict__ T3) {
    const float* W; u16* T;
    switch (blockIdx.z) {
        case 0: W = W0; T = T0; break;
        case 1: W = W1; T = T1; break;
        case 2: W = W2; T = T2; break;
        default: W = W3; T = T3; break;
    }
    __shared__ float tile[32][33];
    int n0 = blockIdx.x * 32, k0 = blockIdx.y * 32;
    int tx = threadIdx.x, ty = threadIdx.y;   // block (32,8)
    #pragma unroll
    for (int j = 0; j < 32; j += 8)
        tile[ty + j][tx] = W[(size_t)(k0 + ty + j) * 1024 + n0 + tx];
    __syncthreads();
    #pragma unroll
    for (int j = 0; j < 32; j += 8)
        T[(size_t)(n0 + ty + j) * 1024 + k0 + tx] = f2bf(tile[tx][ty + j]);
}

// ---------------- GEMM: C[8192x1024] = A[8192x1024] * Bt[1024x1024]^T ----------------
// MODE 0: bf16 out [B,H,S,d] (Q,K)  MODE 1: bf16 out [B,H,d,S] (V^T)
// MODE 2: f32 out row-major + bias
template<int MODE>
__global__ __launch_bounds__(256)
void k_gemm(const u16* __restrict__ A, const u16* __restrict__ Bt,
            u16* __restrict__ outb, float* __restrict__ outf, const float* __restrict__ bias) {
    __shared__ u16 lA[128 * 64];
    __shared__ u16 lB[128 * 64];
    const int lane = threadIdx.x & 63, wave = threadIdx.x >> 6;
    const int lo = lane & 15, hi = lane >> 4;
    const int m0 = blockIdx.x * 128, n0 = blockIdx.y * 128;
    const int wr = wave >> 1, wc = wave & 1;
    const int srow = lane >> 3;
    const int scol = (lane & 7) * 8;

    f32x4 acc[4][4];
    #pragma unroll
    for (int mi = 0; mi < 4; mi++)
        #pragma unroll
        for (int ni = 0; ni < 4; ni++)
            acc[mi][ni] = f32x4{0.f, 0.f, 0.f, 0.f};

    for (int k0 = 0; k0 < 1024; k0 += 64) {
        __syncthreads();
        #pragma unroll
        for (int i = 0; i < 4; i++) {
            int c = i * 4 + wave;
            int r = c * 8 + srow;
            gld_lds16(A  + (size_t)(m0 + r) * 1024 + k0 + scol, lA + c * 512);
            gld_lds16(Bt + (size_t)(n0 + r) * 1024 + k0 + scol, lB + c * 512);
        }
        __syncthreads();
        #pragma unroll
        for (int kk = 0; kk < 2; kk++) {
            short8 af[4], bf[4];
            #pragma unroll
            for (int mi = 0; mi < 4; mi++)
                af[mi] = ld8(lA + (wr * 64 + mi * 16 + lo) * 64 + kk * 32 + hi * 8);
            #pragma unroll
            for (int ni = 0; ni < 4; ni++)
                bf[ni] = ld8(lB + (wc * 64 + ni * 16 + lo) * 64 + kk * 32 + hi * 8);
            #pragma unroll
            for (int mi = 0; mi < 4; mi++)
                #pragma unroll
                for (int ni = 0; ni < 4; ni++)
                    acc[mi][ni] = __builtin_amdgcn_mfma_f32_16x16x32_bf16(
                        af[mi], bf[ni], acc[mi][ni], 0, 0, 0);
        }
    }

    #pragma unroll
    for (int mi = 0; mi < 4; mi++) {
        #pragma unroll
        for (int ni = 0; ni < 4; ni++) {
            #pragma unroll
            for (int r = 0; r < 4; r++) {
                int row = m0 + wr * 64 + mi * 16 + hi * 4 + r;
                int col = n0 + wc * 64 + ni * 16 + lo;
                float v = acc[mi][ni][r];
                if (MODE == 2) {
                    outf[(size_t)row * 1024 + col] = v + bias[col];
                } else {
                    int b = row >> 11, s = row & 2047, h = col >> 6, dh = col & 63;
                    if (MODE == 0)
                        outb[((size_t)(b * 16 + h) * 2048 + s) * 64 + dh] = f2bf(v);
                    else
                        outb[((size_t)(b * 16 + h) * 64 + dh) * 2048 + s] = f2bf(v);
                }
            }
        }
    }
}

// ---------------- flash attention ----------------
// grid (bh=64, qt=8), block 512 (8 waves x 32 q-rows = 256 rows/block).
// K/V tiles double-buffered in LDS (global_load_lds, XOR-swizzled layout),
// DPP row reduces, deferred denominator reduce.
__global__ __launch_bounds__(512, 4)
void k_attn(const u16* __restrict__ Q, const u16* __restrict__ K,
            const u16* __restrict__ Vt, u16* __restrict__ O) {
    const int lane = threadIdx.x & 63, wave = threadIdx.x >> 6;   // 8 waves
    const int lo = lane & 15, hi = lane >> 4;
    const int bh = blockIdx.x, qt = blockIdx.y;   // flat%8 = bh%8 -> same-head blocks share XCD
    const u16* q  = Q  + (size_t)bh * (2048 * 64);
    const u16* k  = K  + (size_t)bh * (2048 * 64);
    const u16* vt = Vt + (size_t)bh * (64 * 2048);

    __shared__ u16 lK[2][64 * 64];   // [kv][d], swizzled: byte = row*128 + (bc ^ ((row&7)<<4))
    __shared__ u16 lV[2][64 * 64];   // [d][kv], same swizzle
    __shared__ u16 Pl[8][32 * 64];   // per-wave P, same swizzle
    u16* pw = Pl[wave];

    const int q0 = qt * 256 + wave * 32;
    const float SL = 0.18033688011112042f;   // 0.125 * log2(e)

    // staging: wave w stages rows w*8..w*8+7 of each tile; linear LDS dest,
    // inverse-swizzled global source (rule: both-sides-or-neither)
    const int srow = (wave << 3) + (lane >> 3);          // tile row this lane fills
    const int ssw  = ((lane & 7) ^ (srow & 7)) << 3;     // swizzled source elem offset
    const u16* kbase = k  + (size_t)srow * 64   + ssw;   // + kv0*64 per tile
    const u16* vbase = vt + (size_t)srow * 2048 + ssw;   // + kv0 per tile

    // Q fragments hoisted (A-frag: row=lo, k=hi*8+j)
    short8 qf[2][2];
    #pragma unroll
    for (int s = 0; s < 2; s++)
        #pragma unroll
        for (int kk = 0; kk < 2; kk++)
            qf[s][kk] = ld8(q + (size_t)(q0 + s * 16 + lo) * 64 + kk * 32 + hi * 8);

    f32x4 acc[2][4];
    float m2[2][4], lp[2][4];
    #pragma unroll
    for (int s = 0; s < 2; s++) {
        #pragma unroll
        for (int dt = 0; dt < 4; dt++) acc[s][dt] = f32x4{0.f, 0.f, 0.f, 0.f};
        #pragma unroll
        for (int r = 0; r < 4; r++) { m2[s][r] = -1e30f; lp[s][r] = 0.f; }
    }

    // prologue: stage tile 0 into buf 0
    gld_lds16(kbase, lK[0] + (wave << 9));
    gld_lds16(vbase, lV[0] + (wave << 9));
    __syncthreads();   // drains vmcnt + barrier

    int cur = 0;
    for (int t = 0; t < 32; t++) {
        // prefetch next tile into the other buffer (overlaps with compute)
        if (t + 1 < 32) {
            int kv = (t + 1) << 6;
            gld_lds16(kbase + (size_t)kv * 64, lK[cur ^ 1] + (wave << 9));
            gld_lds16(vbase + kv,              lV[cur ^ 1] + (wave << 9));
        }
        const char* Kc = (const char*)lK[cur];
        const char* Vc = (const char*)lV[cur];

        #pragma unroll
        for (int s = 0; s < 2; s++) {
            // ---- S = Q K^T ----
            f32x4 sc[4];
            #pragma unroll
            for (int ct = 0; ct < 4; ct++) sc[ct] = f32x4{0.f, 0.f, 0.f, 0.f};
            #pragma unroll
            for (int kk = 0; kk < 2; kk++) {
                #pragma unroll
                for (int ct = 0; ct < 4; ct++) {
                    int row = ct * 16 + lo;
                    short8 kf = *(const short8*)(Kc + row * 128 +
                        (((kk << 6) + (hi << 4)) ^ ((row & 7) << 4)));
                    sc[ct] = __builtin_amdgcn_mfma_f32_16x16x32_bf16(qf[s][kk], kf, sc[ct], 0, 0, 0);
                }
            }
            // ---- online softmax (rows at hi*4+r), DPP reduce over lo lanes ----
            #pragma unroll
            for (int r = 0; r < 4; r++) {
                float mx = fmaxf(fmaxf(sc[0][r], sc[1][r]), fmaxf(sc[2][r], sc[3][r]));
                mx = fmaxf(mx, DPPF(mx, 0xB1));
                mx = fmaxf(mx, DPPF(mx, 0x4E));
                mx = fmaxf(mx, DPPF(mx, 0x124));
                mx = fmaxf(mx, DPPF(mx, 0x128));
                float mn = fmaxf(m2[s][r], mx * SL);
                float al = EXP2(m2[s][r] - mn);
                m2[s][r] = mn;
                int row = (s << 4) + (hi << 2) + r;
                int rsw = (row & 7) << 4;
                float sum = 0.f;
                #pragma unroll
                for (int ct = 0; ct < 4; ct++) {
                    float e = EXP2(sc[ct][r] * SL - mn);
                    uint32_t pb = f2bf(e);          // bf16 round BEFORE sum (num/den correlate)
                    sum += bf2f((u16)pb);
                    uint32_t nb_ = DPPU(pb, 0xB1);  // neighbor's bf16 (xor1)
                    if (!(lane & 1)) {
                        int byteoff = (row * 128 + ((ct * 16 + lo) << 1)) ^ rsw;
                        *(uint32_t*)((char*)pw + byteoff) = pb | (nb_ << 16);
                    }
                }
                lp[s][r] = lp[s][r] * al + sum;     // per-lane partial; reduce at end
                #pragma unroll
                for (int dt = 0; dt < 4; dt++) acc[s][dt][r] *= al;
            }
            // ---- O += P V ----
            #pragma unroll
            for (int nb = 0; nb < 2; nb++) {
                int prow = (s << 4) + lo;
                short8 pa = *(const short8*)((const char*)pw +
                    ((prow * 128 + ((nb << 6) + (hi << 4))) ^ ((prow & 7) << 4)));
                #pragma unroll
                for (int dt = 0; dt < 4; dt++) {
                    int vrow = dt * 16 + lo;
                    short8 vf = *(const short8*)(Vc + vrow * 128 +
                        (((nb << 6) + (hi << 4)) ^ ((vrow & 7) << 4)));
                    acc[s][dt] = __builtin_amdgcn_mfma_f32_16x16x32_bf16(pa, vf, acc[s][dt], 0, 0, 0);
                }
            }
        }
        __syncthreads();   // drains prefetch vmcnt; protects buffer swap + P reuse
        cur ^= 1;
    }

    // ---- final denominator reduce + write [B,S,H*d] bf16 ----
    const int b = bh >> 4, h = bh & 15;
    #pragma unroll
    for (int s = 0; s < 2; s++) {
        float ln[4];
        #pragma unroll
        for (int r = 0; r < 4; r++) {
            float v = lp[s][r];
            v += DPPF(v, 0xB1);
            v += DPPF(v, 0x4E);
            v += DPPF(v, 0x124);
            v += DPPF(v, 0x128);
            ln[r] = 1.0f / v;
        }
        #pragma unroll
        for (int dt = 0; dt < 4; dt++) {
            #pragma unroll
            for (int r = 0; r < 4; r++) {
                float o = acc[s][dt][r] * ln[r];
                int rowg = q0 + s * 16 + (hi << 2) + r;
                int col  = dt * 16 + lo;
                O[((size_t)(b * 2048 + rowg)) * 1024 + h * 64 + col] = f2bf(o);
            }
        }
    }
}

// ---------------- launcher ----------------
extern "C" void kernel_launch(void* const* d_in, const int* in_sizes, int n_in,
                              void* d_out, int out_size, void* d_ws, size_t ws_size,
                              hipStream_t stream) {
    const float* X  = (const float*)d_in[0];
    const float* Wq = (const float*)d_in[1];
    const float* Wk = (const float*)d_in[2];
    const float* Wv = (const float*)d_in[3];
    const float* Wo = (const float*)d_in[4];
    const float* bo = (const float*)d_in[5];
    float* out = (float*)d_out;
    char* ws = (char*)d_ws;
    const size_t MB = 1024 * 1024;
    u16* Xb  = (u16*)(ws + 0 * MB);
    u16* WqT = (u16*)(ws + 16 * MB);
    u16* WkT = (u16*)(ws + 18 * MB);
    u16* WvT = (u16*)(ws + 20 * MB);
    u16* WoT = (u16*)(ws + 22 * MB);
    u16* Qb  = (u16*)(ws + 24 * MB);
    u16* Kb  = (u16*)(ws + 40 * MB);
    u16* Vt  = (u16*)(ws + 56 * MB);
    u16* Ab  = (u16*)(ws + 72 * MB);

    k_convert<<<8192, 256, 0, stream>>>(X, Xb, 8192 * 1024 / 4);
    k_transpose4<<<dim3(32, 32, 4), dim3(32, 8), 0, stream>>>(Wq, Wk, Wv, Wo, WqT, WkT, WvT, WoT);
    dim3 g(64, 8), blk(256);
    k_gemm<0><<<g, blk, 0, stream>>>(Xb, WqT, Qb, nullptr, nullptr);
    k_gemm<0><<<g, blk, 0, stream>>>(Xb, WkT, Kb, nullptr, nullptr);
    k_gemm<1><<<g, blk, 0, stream>>>(Xb, WvT, Vt, nullptr, nullptr);
    k_attn<<<dim3(64, 8), 512, 0, stream>>>(Qb, Kb, Vt, Ab);
    k_gemm<2><<<g, blk, 0, stream>>>(Ab, WoT, nullptr, out, bo);
}

// Round 4
// 403.145 us; speedup vs baseline: 2.2145x; 2.0808x over previous
//
#include <hip/hip_runtime.h>
#include <hip/hip_bf16.h>
#include <stdint.h>

// CrossAttention forward, MI355X/gfx950.
// R4: k_attn register fix — drop forced min-occupancy (R3's launch_bounds(512,4)
// capped the unified VGPR+AGPR file at 128 -> per-iteration scratch spill,
// 1.78 GB HBM traffic/dispatch). P LDS buffer halved (s-phases reuse it).

typedef unsigned short u16;
typedef __attribute__((ext_vector_type(8))) short short8;   // 8 x bf16
typedef __attribute__((ext_vector_type(4))) float f32x4;
typedef __attribute__((ext_vector_type(4))) unsigned short us4;

#define AS1 __attribute__((address_space(1)))
#define AS3 __attribute__((address_space(3)))

#if __has_builtin(__builtin_amdgcn_exp2f)
#define EXP2(x) __builtin_amdgcn_exp2f(x)
#else
#define EXP2(x) exp2f(x)
#endif

// DPP cross-lane (VALU pipe, not LDS): ctrl must be a constant.
// 0xB1 = quad_perm[1,0,3,2] (xor1), 0x4E = quad_perm[2,3,0,1] (xor2),
// 0x124 = row_ror:4, 0x128 = row_ror:8  (row = 16 lanes)
#define DPPF(x, ctrl) (__builtin_bit_cast(float, __builtin_amdgcn_update_dpp( \
    0, __builtin_bit_cast(int, (float)(x)), (ctrl), 0xf, 0xf, true)))
#define DPPU(x, ctrl) ((uint32_t)__builtin_amdgcn_update_dpp( \
    0, (int)(x), (ctrl), 0xf, 0xf, true))

__device__ __forceinline__ u16 f2bf(float x) {
    union { float f; uint32_t u; } c; c.f = x;
    uint32_t r = c.u + 0x7fffu + ((c.u >> 16) & 1u);   // RNE
    return (u16)(r >> 16);
}

__device__ __forceinline__ float bf2f(u16 x) {
    union { uint32_t u; float f; } c; c.u = (uint32_t)x << 16;
    return c.f;
}

__device__ __forceinline__ short8 ld8(const u16* p) { return *(const short8*)p; }

__device__ __forceinline__ void gld_lds16(const u16* g, u16* l) {
    __builtin_amdgcn_global_load_lds((const AS1 void*)g, (AS3 void*)l, 16, 0, 0);
}

// ---------------- convert f32 -> bf16 (vectorized x4) ----------------
__global__ void k_convert(const float* __restrict__ in, u16* __restrict__ out, int n4) {
    int i = blockIdx.x * blockDim.x + threadIdx.x;
    if (i >= n4) return;
    float4 v = *((const float4*)in + i);
    us4 o = { f2bf(v.x), f2bf(v.y), f2bf(v.z), f2bf(v.w) };
    *((us4*)out + i) = o;
}

// ---------------- transpose 4 weights, f32[K][N] -> bf16[N][K] ----------------
__global__ void k_transpose4(const float* __restrict__ W0, const float* __restrict__ W1,
                             const float* __restrict__ W2, const float* __restrict__ W3,
                             u16* __restrict__ T0, u16* __restrict__ T1,
                             u16* __restrict__ T2, u16* __restrict__ T3) {
    const float* W; u16* T;
    switch (blockIdx.z) {
        case 0: W = W0; T = T0; break;
        case 1: W = W1; T = T1; break;
        case 2: W = W2; T = T2; break;
        default: W = W3; T = T3; break;
    }
    __shared__ float tile[32][33];
    int n0 = blockIdx.x * 32, k0 = blockIdx.y * 32;
    int tx = threadIdx.x, ty = threadIdx.y;   // block (32,8)
    #pragma unroll
    for (int j = 0; j < 32; j += 8)
        tile[ty + j][tx] = W[(size_t)(k0 + ty + j) * 1024 + n0 + tx];
    __syncthreads();
    #pragma unroll
    for (int j = 0; j < 32; j += 8)
        T[(size_t)(n0 + ty + j) * 1024 + k0 + tx] = f2bf(tile[tx][ty + j]);
}

// ---------------- GEMM: C[8192x1024] = A[8192x1024] * Bt[1024x1024]^T ----------------
// MODE 0: bf16 out [B,H,S,d] (Q,K)  MODE 1: bf16 out [B,H,d,S] (V^T)
// MODE 2: f32 out row-major + bias
template<int MODE>
__global__ __launch_bounds__(256)
void k_gemm(const u16* __restrict__ A, const u16* __restrict__ Bt,
            u16* __restrict__ outb, float* __restrict__ outf, const float* __restrict__ bias) {
    __shared__ u16 lA[128 * 64];
    __shared__ u16 lB[128 * 64];
    const int lane = threadIdx.x & 63, wave = threadIdx.x >> 6;
    const int lo = lane & 15, hi = lane >> 4;
    const int m0 = blockIdx.x * 128, n0 = blockIdx.y * 128;
    const int wr = wave >> 1, wc = wave & 1;
    const int srow = lane >> 3;
    const int scol = (lane & 7) * 8;

    f32x4 acc[4][4];
    #pragma unroll
    for (int mi = 0; mi < 4; mi++)
        #pragma unroll
        for (int ni = 0; ni < 4; ni++)
            acc[mi][ni] = f32x4{0.f, 0.f, 0.f, 0.f};

    for (int k0 = 0; k0 < 1024; k0 += 64) {
        __syncthreads();
        #pragma unroll
        for (int i = 0; i < 4; i++) {
            int c = i * 4 + wave;
            int r = c * 8 + srow;
            gld_lds16(A  + (size_t)(m0 + r) * 1024 + k0 + scol, lA + c * 512);
            gld_lds16(Bt + (size_t)(n0 + r) * 1024 + k0 + scol, lB + c * 512);
        }
        __syncthreads();
        #pragma unroll
        for (int kk = 0; kk < 2; kk++) {
            short8 af[4], bf[4];
            #pragma unroll
            for (int mi = 0; mi < 4; mi++)
                af[mi] = ld8(lA + (wr * 64 + mi * 16 + lo) * 64 + kk * 32 + hi * 8);
            #pragma unroll
            for (int ni = 0; ni < 4; ni++)
                bf[ni] = ld8(lB + (wc * 64 + ni * 16 + lo) * 64 + kk * 32 + hi * 8);
            #pragma unroll
            for (int mi = 0; mi < 4; mi++)
                #pragma unroll
                for (int ni = 0; ni < 4; ni++)
                    acc[mi][ni] = __builtin_amdgcn_mfma_f32_16x16x32_bf16(
                        af[mi], bf[ni], acc[mi][ni], 0, 0, 0);
        }
    }

    #pragma unroll
    for (int mi = 0; mi < 4; mi++) {
        #pragma unroll
        for (int ni = 0; ni < 4; ni++) {
            #pragma unroll
            for (int r = 0; r < 4; r++) {
                int row = m0 + wr * 64 + mi * 16 + hi * 4 + r;
                int col = n0 + wc * 64 + ni * 16 + lo;
                float v = acc[mi][ni][r];
                if (MODE == 2) {
                    outf[(size_t)row * 1024 + col] = v + bias[col];
                } else {
                    int b = row >> 11, s = row & 2047, h = col >> 6, dh = col & 63;
                    if (MODE == 0)
                        outb[((size_t)(b * 16 + h) * 2048 + s) * 64 + dh] = f2bf(v);
                    else
                        outb[((size_t)(b * 16 + h) * 64 + dh) * 2048 + s] = f2bf(v);
                }
            }
        }
    }
}

// ---------------- flash attention ----------------
// grid (bh=64, qt=8), block 512 (8 waves x 32 q-rows = 256 rows/block).
// K/V tiles double-buffered in LDS (global_load_lds, XOR-swizzled layout),
// DPP row reduces, deferred denominator reduce. NO min-waves bound: R3's
// (512,4) forced a 128-reg unified budget -> per-iteration scratch spill.
__global__ __launch_bounds__(512)
void k_attn(const u16* __restrict__ Q, const u16* __restrict__ K,
            const u16* __restrict__ Vt, u16* __restrict__ O) {
    const int lane = threadIdx.x & 63, wave = threadIdx.x >> 6;   // 8 waves
    const int lo = lane & 15, hi = lane >> 4;
    const int bh = blockIdx.x, qt = blockIdx.y;   // flat%8 = bh%8 -> same-head blocks share XCD
    const u16* q  = Q  + (size_t)bh * (2048 * 64);
    const u16* k  = K  + (size_t)bh * (2048 * 64);
    const u16* vt = Vt + (size_t)bh * (64 * 2048);

    __shared__ u16 lK[2][64 * 64];   // [kv][d], swizzled: byte = row*128 + (bc ^ ((row&7)<<4))
    __shared__ u16 lV[2][64 * 64];   // [d][kv], same swizzle
    __shared__ u16 Pl[8][16 * 64];   // per-wave P (16 rows; s-phases reuse it)
    u16* pw = Pl[wave];

    const int q0 = qt * 256 + wave * 32;
    const float SL = 0.18033688011112042f;   // 0.125 * log2(e)

    // staging: wave w stages rows w*8..w*8+7; linear LDS dest,
    // inverse-swizzled global source (both-sides-or-neither rule)
    const int srow = (wave << 3) + (lane >> 3);
    const int ssw  = ((lane & 7) ^ (srow & 7)) << 3;
    const u16* kbase = k  + (size_t)srow * 64   + ssw;
    const u16* vbase = vt + (size_t)srow * 2048 + ssw;

    // Q fragments hoisted (A-frag: row=lo, k=hi*8+j)
    short8 qf[2][2];
    #pragma unroll
    for (int s = 0; s < 2; s++)
        #pragma unroll
        for (int kk = 0; kk < 2; kk++)
            qf[s][kk] = ld8(q + (size_t)(q0 + s * 16 + lo) * 64 + kk * 32 + hi * 8);

    f32x4 acc[2][4];
    float m2[2][4], lp[2][4];
    #pragma unroll
    for (int s = 0; s < 2; s++) {
        #pragma unroll
        for (int dt = 0; dt < 4; dt++) acc[s][dt] = f32x4{0.f, 0.f, 0.f, 0.f};
        #pragma unroll
        for (int r = 0; r < 4; r++) { m2[s][r] = -1e30f; lp[s][r] = 0.f; }
    }

    // prologue: stage tile 0 into buf 0
    gld_lds16(kbase, lK[0] + (wave << 9));
    gld_lds16(vbase, lV[0] + (wave << 9));
    __syncthreads();

    int cur = 0;
    for (int t = 0; t < 32; t++) {
        if (t + 1 < 32) {
            int kv = (t + 1) << 6;
            gld_lds16(kbase + (size_t)kv * 64, lK[cur ^ 1] + (wave << 9));
            gld_lds16(vbase + kv,              lV[cur ^ 1] + (wave << 9));
        }
        const char* Kc = (const char*)lK[cur];
        const char* Vc = (const char*)lV[cur];

        #pragma unroll
        for (int s = 0; s < 2; s++) {
            // ---- S = Q K^T ----
            f32x4 sc[4];
            #pragma unroll
            for (int ct = 0; ct < 4; ct++) sc[ct] = f32x4{0.f, 0.f, 0.f, 0.f};
            #pragma unroll
            for (int kk = 0; kk < 2; kk++) {
                #pragma unroll
                for (int ct = 0; ct < 4; ct++) {
                    int row = ct * 16 + lo;
                    short8 kf = *(const short8*)(Kc + row * 128 +
                        (((kk << 6) + (hi << 4)) ^ ((row & 7) << 4)));
                    sc[ct] = __builtin_amdgcn_mfma_f32_16x16x32_bf16(qf[s][kk], kf, sc[ct], 0, 0, 0);
                }
            }
            // ---- online softmax (rows at hi*4+r), DPP reduce over lo lanes ----
            #pragma unroll
            for (int r = 0; r < 4; r++) {
                float mx = fmaxf(fmaxf(sc[0][r], sc[1][r]), fmaxf(sc[2][r], sc[3][r]));
                mx = fmaxf(mx, DPPF(mx, 0xB1));
                mx = fmaxf(mx, DPPF(mx, 0x4E));
                mx = fmaxf(mx, DPPF(mx, 0x124));
                mx = fmaxf(mx, DPPF(mx, 0x128));
                float mn = fmaxf(m2[s][r], mx * SL);
                float al = EXP2(m2[s][r] - mn);
                m2[s][r] = mn;
                int row = (hi << 2) + r;            // s-relative P row (buffer reused per s)
                int rsw = (row & 7) << 4;
                float sum = 0.f;
                #pragma unroll
                for (int ct = 0; ct < 4; ct++) {
                    float e = EXP2(sc[ct][r] * SL - mn);
                    uint32_t pb = f2bf(e);          // bf16 round BEFORE sum (num/den correlate)
                    sum += bf2f((u16)pb);
                    uint32_t nb_ = DPPU(pb, 0xB1);  // neighbor's bf16 (xor1)
                    if (!(lane & 1)) {
                        int byteoff = (row * 128 + ((ct * 16 + lo) << 1)) ^ rsw;
                        *(uint32_t*)((char*)pw + byteoff) = pb | (nb_ << 16);
                    }
                }
                lp[s][r] = lp[s][r] * al + sum;     // per-lane partial; reduce at end
                #pragma unroll
                for (int dt = 0; dt < 4; dt++) acc[s][dt][r] *= al;
            }
            // ---- O += P V ----
            #pragma unroll
            for (int nb = 0; nb < 2; nb++) {
                int prow = lo;
                short8 pa = *(const short8*)((const char*)pw +
                    ((prow * 128 + ((nb << 6) + (hi << 4))) ^ ((prow & 7) << 4)));
                #pragma unroll
                for (int dt = 0; dt < 4; dt++) {
                    int vrow = dt * 16 + lo;
                    short8 vf = *(const short8*)(Vc + vrow * 128 +
                        (((nb << 6) + (hi << 4)) ^ ((vrow & 7) << 4)));
                    acc[s][dt] = __builtin_amdgcn_mfma_f32_16x16x32_bf16(pa, vf, acc[s][dt], 0, 0, 0);
                }
            }
        }
        __syncthreads();   // drains prefetch vmcnt; protects buffer swap
        cur ^= 1;
    }

    // ---- final denominator reduce + write [B,S,H*d] bf16 ----
    const int b = bh >> 4, h = bh & 15;
    #pragma unroll
    for (int s = 0; s < 2; s++) {
        float ln[4];
        #pragma unroll
        for (int r = 0; r < 4; r++) {
            float v = lp[s][r];
            v += DPPF(v, 0xB1);
            v += DPPF(v, 0x4E);
            v += DPPF(v, 0x124);
            v += DPPF(v, 0x128);
            ln[r] = 1.0f / v;
        }
        #pragma unroll
        for (int dt = 0; dt < 4; dt++) {
            #pragma unroll
            for (int r = 0; r < 4; r++) {
                float o = acc[s][dt][r] * ln[r];
                int rowg = q0 + s * 16 + (hi << 2) + r;
                int col  = dt * 16 + lo;
                O[((size_t)(b * 2048 + rowg)) * 1024 + h * 64 + col] = f2bf(o);
            }
        }
    }
}

// ---------------- launcher ----------------
extern "C" void kernel_launch(void* const* d_in, const int* in_sizes, int n_in,
                              void* d_out, int out_size, void* d_ws, size_t ws_size,
                              hipStream_t stream) {
    const float* X  = (const float*)d_in[0];
    const float* Wq = (const float*)d_in[1];
    const float* Wk = (const float*)d_in[2];
    const float* Wv = (const float*)d_in[3];
    const float* Wo = (const float*)d_in[4];
    const float* bo = (const float*)d_in[5];
    float* out = (float*)d_out;
    char* ws = (char*)d_ws;
    const size_t MB = 1024 * 1024;
    u16* Xb  = (u16*)(ws + 0 * MB);
    u16* WqT = (u16*)(ws + 16 * MB);
    u16* WkT = (u16*)(ws + 18 * MB);
    u16* WvT = (u16*)(ws + 20 * MB);
    u16* WoT = (u16*)(ws + 22 * MB);
    u16* Qb  = (u16*)(ws + 24 * MB);
    u16* Kb  = (u16*)(ws + 40 * MB);
    u16* Vt  = (u16*)(ws + 56 * MB);
    u16* Ab  = (u16*)(ws + 72 * MB);

    k_convert<<<8192, 256, 0, stream>>>(X, Xb, 8192 * 1024 / 4);
    k_transpose4<<<dim3(32, 32, 4), dim3(32, 8), 0, stream>>>(Wq, Wk, Wv, Wo, WqT, WkT, WvT, WoT);
    dim3 g(64, 8), blk(256);
    k_gemm<0><<<g, blk, 0, stream>>>(Xb, WqT, Qb, nullptr, nullptr);
    k_gemm<0><<<g, blk, 0, stream>>>(Xb, WkT, Kb, nullptr, nullptr);
    k_gemm<1><<<g, blk, 0, stream>>>(Xb, WvT, Vt, nullptr, nullptr);
    k_attn<<<dim3(64, 8), 512, 0, stream>>>(Qb, Kb, Vt, Ab);
    k_gemm<2><<<g, blk, 0, stream>>>(Ab, WoT, nullptr, out, bo);
}

// Round 6
// 332.535 us; speedup vs baseline: 2.6848x; 1.2123x over previous
//
#include <hip/hip_runtime.h>
#include <hip/hip_bf16.h>
#include <stdint.h>

// CrossAttention forward, MI355X/gfx950.
// R6 = verified R4 kernel with ONLY the softmax subsystem swapped:
// S^T = mfma(K,Q) -> per-lane softmax (q = lane&15), shfl_xor reduces,
// f2bf packing (no cvt_pk asm, no ds_swizzle), al/l redistributed by shfl.
// PV, accumulator orientation, epilogue: verbatim R4 (verified).

typedef unsigned short u16;
typedef __attribute__((ext_vector_type(8))) short short8;   // 8 x bf16
typedef __attribute__((ext_vector_type(4))) float f32x4;
typedef __attribute__((ext_vector_type(4))) unsigned short us4;

#define AS1 __attribute__((address_space(1)))
#define AS3 __attribute__((address_space(3)))

#if __has_builtin(__builtin_amdgcn_exp2f)
#define EXP2(x) __builtin_amdgcn_exp2f(x)
#else
#define EXP2(x) exp2f(x)
#endif

__device__ __forceinline__ u16 f2bf(float x) {
    union { float f; uint32_t u; } c; c.f = x;
    uint32_t r = c.u + 0x7fffu + ((c.u >> 16) & 1u);   // RNE
    return (u16)(r >> 16);
}

__device__ __forceinline__ float bf2f(u16 x) {
    union { uint32_t u; float f; } c; c.u = (uint32_t)x << 16;
    return c.f;
}

__device__ __forceinline__ short8 ld8(const u16* p) { return *(const short8*)p; }

__device__ __forceinline__ void gld_lds16(const u16* g, u16* l) {
    __builtin_amdgcn_global_load_lds((const AS1 void*)g, (AS3 void*)l, 16, 0, 0);
}

// ---------------- convert f32 -> bf16 (vectorized x4) ----------------
__global__ void k_convert(const float* __restrict__ in, u16* __restrict__ out, int n4) {
    int i = blockIdx.x * blockDim.x + threadIdx.x;
    if (i >= n4) return;
    float4 v = *((const float4*)in + i);
    us4 o = { f2bf(v.x), f2bf(v.y), f2bf(v.z), f2bf(v.w) };
    *((us4*)out + i) = o;
}

// ---------------- transpose 4 weights, f32[K][N] -> bf16[N][K] ----------------
__global__ void k_transpose4(const float* __restrict__ W0, const float* __restrict__ W1,
                             const float* __restrict__ W2, const float* __restrict__ W3,
                             u16* __restrict__ T0, u16* __restrict__ T1,
                             u16* __restrict__ T2, u16* __restrict__ T3) {
    const float* W; u16* T;
    switch (blockIdx.z) {
        case 0: W = W0; T = T0; break;
        case 1: W = W1; T = T1; break;
        case 2: W = W2; T = T2; break;
        default: W = W3; T = T3; break;
    }
    __shared__ float tile[32][33];
    int n0 = blockIdx.x * 32, k0 = blockIdx.y * 32;
    int tx = threadIdx.x, ty = threadIdx.y;   // block (32,8)
    #pragma unroll
    for (int j = 0; j < 32; j += 8)
        tile[ty + j][tx] = W[(size_t)(k0 + ty + j) * 1024 + n0 + tx];
    __syncthreads();
    #pragma unroll
    for (int j = 0; j < 32; j += 8)
        T[(size_t)(n0 + ty + j) * 1024 + k0 + tx] = f2bf(tile[tx][ty + j]);
}

// ---------------- fused QKV GEMM ----------------
// grid (64, 8, 3): z=0 -> Qb [B,H,S,d], z=1 -> Kb [B,H,S,d], z=2 -> Vt [B,H,d,S]
__global__ __launch_bounds__(256)
void k_gemm_qkv(const u16* __restrict__ A,
                const u16* __restrict__ BQ, const u16* __restrict__ BK,
                const u16* __restrict__ BV,
                u16* __restrict__ Qb, u16* __restrict__ Kb, u16* __restrict__ Vtw) {
    const int z = blockIdx.z;
    const u16* Bt = (z == 0) ? BQ : (z == 1) ? BK : BV;
    __shared__ u16 lA[128 * 64];
    __shared__ u16 lB[128 * 64];
    const int lane = threadIdx.x & 63, wave = threadIdx.x >> 6;
    const int lo = lane & 15, hi = lane >> 4;
    const int m0 = blockIdx.x * 128, n0 = blockIdx.y * 128;
    const int wr = wave >> 1, wc = wave & 1;
    const int srow = lane >> 3;
    const int scol = (lane & 7) * 8;

    f32x4 acc[4][4];
    #pragma unroll
    for (int mi = 0; mi < 4; mi++)
        #pragma unroll
        for (int ni = 0; ni < 4; ni++)
            acc[mi][ni] = f32x4{0.f, 0.f, 0.f, 0.f};

    for (int k0 = 0; k0 < 1024; k0 += 64) {
        __syncthreads();
        #pragma unroll
        for (int i = 0; i < 4; i++) {
            int c = i * 4 + wave;
            int r = c * 8 + srow;
            gld_lds16(A  + (size_t)(m0 + r) * 1024 + k0 + scol, lA + c * 512);
            gld_lds16(Bt + (size_t)(n0 + r) * 1024 + k0 + scol, lB + c * 512);
        }
        __syncthreads();
        #pragma unroll
        for (int kk = 0; kk < 2; kk++) {
            short8 af[4], bf[4];
            #pragma unroll
            for (int mi = 0; mi < 4; mi++)
                af[mi] = ld8(lA + (wr * 64 + mi * 16 + lo) * 64 + kk * 32 + hi * 8);
            #pragma unroll
            for (int ni = 0; ni < 4; ni++)
                bf[ni] = ld8(lB + (wc * 64 + ni * 16 + lo) * 64 + kk * 32 + hi * 8);
            #pragma unroll
            for (int mi = 0; mi < 4; mi++)
                #pragma unroll
                for (int ni = 0; ni < 4; ni++)
                    acc[mi][ni] = __builtin_amdgcn_mfma_f32_16x16x32_bf16(
                        af[mi], bf[ni], acc[mi][ni], 0, 0, 0);
        }
    }

    u16* outb = (z == 0) ? Qb : (z == 1) ? Kb : Vtw;
    #pragma unroll
    for (int mi = 0; mi < 4; mi++) {
        #pragma unroll
        for (int ni = 0; ni < 4; ni++) {
            #pragma unroll
            for (int r = 0; r < 4; r++) {
                int row = m0 + wr * 64 + mi * 16 + hi * 4 + r;
                int col = n0 + wc * 64 + ni * 16 + lo;
                float v = acc[mi][ni][r];
                int b = row >> 11, s = row & 2047, h = col >> 6, dh = col & 63;
                if (z < 2)
                    outb[((size_t)(b * 16 + h) * 2048 + s) * 64 + dh] = f2bf(v);
                else
                    outb[((size_t)(b * 16 + h) * 64 + dh) * 2048 + s] = f2bf(v);
            }
        }
    }
}

// ---------------- output GEMM: f32 out + bias ----------------
__global__ __launch_bounds__(256)
void k_gemm_out(const u16* __restrict__ A, const u16* __restrict__ Bt,
                float* __restrict__ outf, const float* __restrict__ bias) {
    __shared__ u16 lA[128 * 64];
    __shared__ u16 lB[128 * 64];
    const int lane = threadIdx.x & 63, wave = threadIdx.x >> 6;
    const int lo = lane & 15, hi = lane >> 4;
    const int m0 = blockIdx.x * 128, n0 = blockIdx.y * 128;
    const int wr = wave >> 1, wc = wave & 1;
    const int srow = lane >> 3;
    const int scol = (lane & 7) * 8;

    f32x4 acc[4][4];
    #pragma unroll
    for (int mi = 0; mi < 4; mi++)
        #pragma unroll
        for (int ni = 0; ni < 4; ni++)
            acc[mi][ni] = f32x4{0.f, 0.f, 0.f, 0.f};

    for (int k0 = 0; k0 < 1024; k0 += 64) {
        __syncthreads();
        #pragma unroll
        for (int i = 0; i < 4; i++) {
            int c = i * 4 + wave;
            int r = c * 8 + srow;
            gld_lds16(A  + (size_t)(m0 + r) * 1024 + k0 + scol, lA + c * 512);
            gld_lds16(Bt + (size_t)(n0 + r) * 1024 + k0 + scol, lB + c * 512);
        }
        __syncthreads();
        #pragma unroll
        for (int kk = 0; kk < 2; kk++) {
            short8 af[4], bf[4];
            #pragma unroll
            for (int mi = 0; mi < 4; mi++)
                af[mi] = ld8(lA + (wr * 64 + mi * 16 + lo) * 64 + kk * 32 + hi * 8);
            #pragma unroll
            for (int ni = 0; ni < 4; ni++)
                bf[ni] = ld8(lB + (wc * 64 + ni * 16 + lo) * 64 + kk * 32 + hi * 8);
            #pragma unroll
            for (int mi = 0; mi < 4; mi++)
                #pragma unroll
                for (int ni = 0; ni < 4; ni++)
                    acc[mi][ni] = __builtin_amdgcn_mfma_f32_16x16x32_bf16(
                        af[mi], bf[ni], acc[mi][ni], 0, 0, 0);
        }
    }

    #pragma unroll
    for (int mi = 0; mi < 4; mi++) {
        #pragma unroll
        for (int ni = 0; ni < 4; ni++) {
            #pragma unroll
            for (int r = 0; r < 4; r++) {
                int row = m0 + wr * 64 + mi * 16 + hi * 4 + r;
                int col = n0 + wc * 64 + ni * 16 + lo;
                outf[(size_t)row * 1024 + col] = acc[mi][ni][r] + bias[col];
            }
        }
    }
}

// ---------------- flash attention (swapped QK^T, R4 PV/epilogue) ----------------
// grid (bh=64, qt=8), block 512 (8 waves x 32 q-rows).
// sc = mfma(kf, qf): lane owns S[q=lane&15][kv=ct*16+hi*4+r] -> in-lane softmax.
// P written to the SAME [q][kv] swizzled LDS layout R4 used; PV and epilogue
// are verbatim R4 (verified). al/l redistributed to (hi*4+r) lanes via shfl.
__global__ __launch_bounds__(512)
void k_attn(const u16* __restrict__ Q, const u16* __restrict__ K,
            const u16* __restrict__ Vt, u16* __restrict__ O) {
    const int lane = threadIdx.x & 63, wave = threadIdx.x >> 6;   // 8 waves
    const int lo = lane & 15, hi = lane >> 4;
    const int bh = blockIdx.x, qt = blockIdx.y;
    const u16* q  = Q  + (size_t)bh * (2048 * 64);
    const u16* k  = K  + (size_t)bh * (2048 * 64);
    const u16* vt = Vt + (size_t)bh * (64 * 2048);

    __shared__ u16 lK[2][64 * 64];   // [kv][d], swizzled: byte = row*128 + (bc ^ ((row&7)<<4))
    __shared__ u16 lV[2][64 * 64];   // [d][kv], same swizzle
    __shared__ u16 Pl[8][16 * 64];   // per-wave P [q][kv] bf16, swizzle ^((q&7)<<4)
    char* pwc = (char*)Pl[wave];

    const int q0 = qt * 256 + wave * 32;
    const float SL = 0.18033688011112042f;   // 0.125 * log2(e)
    const int swzlo = (lo & 7) << 4;

    // staging (R4): linear LDS dest, inverse-swizzled global source
    const int srow = (wave << 3) + (lane >> 3);
    const int ssw  = ((lane & 7) ^ (srow & 7)) << 3;
    const u16* kbase = k  + (size_t)srow * 64   + ssw;
    const u16* vbase = vt + (size_t)srow * 2048 + ssw;

    // Q fragments (col=q=lo, k=d=hi*8+j) — same loads as R4
    short8 qf[2][2];
    #pragma unroll
    for (int s = 0; s < 2; s++)
        #pragma unroll
        for (int kk = 0; kk < 2; kk++)
            qf[s][kk] = ld8(q + (size_t)(q0 + s * 16 + lo) * 64 + kk * 32 + hi * 8);

    f32x4 acc[2][4];   // R4 orientation: acc[s][dt][r] = O[q=hi*4+r][d=dt*16+lo]
    #pragma unroll
    for (int s = 0; s < 2; s++)
        #pragma unroll
        for (int dt = 0; dt < 4; dt++) acc[s][dt] = f32x4{0.f, 0.f, 0.f, 0.f};
    float m2[2] = { -1e30f, -1e30f };   // per-lane (q = lo), SL-domain
    float lp[2] = { 0.f, 0.f };         // per-lane partial denominators

    gld_lds16(kbase, lK[0] + (wave << 9));
    gld_lds16(vbase, lV[0] + (wave << 9));
    __syncthreads();

    int cur = 0;
    for (int t = 0; t < 32; t++) {
        if (t + 1 < 32) {
            int kv = (t + 1) << 6;
            gld_lds16(kbase + (size_t)kv * 64, lK[cur ^ 1] + (wave << 9));
            gld_lds16(vbase + kv,              lV[cur ^ 1] + (wave << 9));
        }
        const char* Kc = (const char*)lK[cur];
        const char* Vc = (const char*)lV[cur];

        #pragma unroll
        for (int s = 0; s < 2; s++) {
            // ---- S^T = mfma(K, Q): sc[ct][r] = S[q=lo][kv=ct*16+hi*4+r] ----
            f32x4 sc[4];
            #pragma unroll
            for (int ct = 0; ct < 4; ct++) sc[ct] = f32x4{0.f, 0.f, 0.f, 0.f};
            #pragma unroll
            for (int kk = 0; kk < 2; kk++) {
                #pragma unroll
                for (int ct = 0; ct < 4; ct++) {
                    int row = ct * 16 + lo;
                    short8 kf = *(const short8*)(Kc + row * 128 +
                        (((kk << 6) + (hi << 4)) ^ ((row & 7) << 4)));
                    sc[ct] = __builtin_amdgcn_mfma_f32_16x16x32_bf16(kf, qf[s][kk], sc[ct], 0, 0, 0);
                }
            }
            // ---- per-lane online softmax (q = lo) ----
            float mA = fmaxf(fmaxf(sc[0][0], sc[0][1]), fmaxf(sc[0][2], sc[0][3]));
            float mB = fmaxf(fmaxf(sc[1][0], sc[1][1]), fmaxf(sc[1][2], sc[1][3]));
            float mC = fmaxf(fmaxf(sc[2][0], sc[2][1]), fmaxf(sc[2][2], sc[2][3]));
            float mD = fmaxf(fmaxf(sc[3][0], sc[3][1]), fmaxf(sc[3][2], sc[3][3]));
            float mx = fmaxf(fmaxf(mA, mB), fmaxf(mC, mD));
            mx = fmaxf(mx, __shfl_xor(mx, 16));
            mx = fmaxf(mx, __shfl_xor(mx, 32));
            float mn = fmaxf(m2[s], mx * SL);
            float al = EXP2(m2[s] - mn);
            m2[s] = mn;
            // ---- P = exp2(S*SL - mn), bf16-round before sum; write P LDS ----
            float sum = 0.f;
            #pragma unroll
            for (int ct = 0; ct < 4; ct++) {
                #pragma unroll
                for (int wp = 0; wp < 2; wp++) {
                    float e0 = EXP2(sc[ct][2 * wp]     * SL - mn);
                    float e1 = EXP2(sc[ct][2 * wp + 1] * SL - mn);
                    uint32_t b0 = f2bf(e0), b1 = f2bf(e1);
                    sum += bf2f((u16)b0) + bf2f((u16)b1);
                    *(uint32_t*)(pwc +
                        ((lo * 128 + (ct << 5) + (hi << 3) + (wp << 2)) ^ swzlo)) =
                        b0 | (b1 << 16);
                }
            }
            lp[s] = lp[s] * al + sum;
            asm volatile("" ::: "memory");   // order P stores before P loads
            // ---- rescale acc: al lives at q=lo; acc rows are q=hi*4+r ----
            float alr[4];
            #pragma unroll
            for (int r = 0; r < 4; r++) alr[r] = __shfl(al, (hi << 2) + r);
            #pragma unroll
            for (int dt = 0; dt < 4; dt++)
                #pragma unroll
                for (int r = 0; r < 4; r++) acc[s][dt][r] *= alr[r];
            // ---- O += P V (verbatim R4) ----
            #pragma unroll
            for (int nb = 0; nb < 2; nb++) {
                int prow = lo;
                short8 pa = *(const short8*)(pwc +
                    ((prow * 128 + ((nb << 6) + (hi << 4))) ^ ((prow & 7) << 4)));
                #pragma unroll
                for (int dt = 0; dt < 4; dt++) {
                    int vrow = dt * 16 + lo;
                    short8 vf = *(const short8*)(Vc + vrow * 128 +
                        (((nb << 6) + (hi << 4)) ^ ((vrow & 7) << 4)));
                    acc[s][dt] = __builtin_amdgcn_mfma_f32_16x16x32_bf16(pa, vf, acc[s][dt], 0, 0, 0);
                }
            }
            asm volatile("" ::: "memory");   // order P loads before next-phase stores
        }
        __syncthreads();   // drains prefetch vmcnt; protects K/V buffer swap
        cur ^= 1;
    }

    // ---- final denominator + write [B,S,H*d] bf16 (verbatim R4 epilogue) ----
    const int b = bh >> 4, h = bh & 15;
    #pragma unroll
    for (int s = 0; s < 2; s++) {
        float l = lp[s];
        l += __shfl_xor(l, 16);
        l += __shfl_xor(l, 32);
        float ln[4];
        #pragma unroll
        for (int r = 0; r < 4; r++) ln[r] = 1.0f / __shfl(l, (hi << 2) + r);
        #pragma unroll
        for (int dt = 0; dt < 4; dt++) {
            #pragma unroll
            for (int r = 0; r < 4; r++) {
                float o = acc[s][dt][r] * ln[r];
                int rowg = q0 + s * 16 + (hi << 2) + r;
                int col  = dt * 16 + lo;
                O[((size_t)(b * 2048 + rowg)) * 1024 + h * 64 + col] = f2bf(o);
            }
        }
    }
}

// ---------------- launcher ----------------
extern "C" void kernel_launch(void* const* d_in, const int* in_sizes, int n_in,
                              void* d_out, int out_size, void* d_ws, size_t ws_size,
                              hipStream_t stream) {
    const float* X  = (const float*)d_in[0];
    const float* Wq = (const float*)d_in[1];
    const float* Wk = (const float*)d_in[2];
    const float* Wv = (const float*)d_in[3];
    const float* Wo = (const float*)d_in[4];
    const float* bo = (const float*)d_in[5];
    float* out = (float*)d_out;
    char* ws = (char*)d_ws;
    const size_t MB = 1024 * 1024;
    u16* Xb  = (u16*)(ws + 0 * MB);
    u16* WqT = (u16*)(ws + 16 * MB);
    u16* WkT = (u16*)(ws + 18 * MB);
    u16* WvT = (u16*)(ws + 20 * MB);
    u16* WoT = (u16*)(ws + 22 * MB);
    u16* Qb  = (u16*)(ws + 24 * MB);
    u16* Kb  = (u16*)(ws + 40 * MB);
    u16* Vt  = (u16*)(ws + 56 * MB);
    u16* Ab  = (u16*)(ws + 72 * MB);

    k_convert<<<8192, 256, 0, stream>>>(X, Xb, 8192 * 1024 / 4);
    k_transpose4<<<dim3(32, 32, 4), dim3(32, 8), 0, stream>>>(Wq, Wk, Wv, Wo, WqT, WkT, WvT, WoT);
    k_gemm_qkv<<<dim3(64, 8, 3), 256, 0, stream>>>(Xb, WqT, WkT, WvT, Qb, Kb, Vt);
    k_attn<<<dim3(64, 8), 512, 0, stream>>>(Qb, Kb, Vt, Ab);
    k_gemm_out<<<dim3(64, 8), 256, 0, stream>>>(Ab, WoT, out, bo);
}

// Round 9
// 331.712 us; speedup vs baseline: 2.6914x; 1.0025x over previous
//
#include <hip/hip_runtime.h>
#include <hip/hip_bf16.h>
#include <stdint.h>

// CrossAttention forward, MI355X/gfx950.
// R9 = R6 (verified, 332.5us) with ONE change: QKV GEMM merged into a single
// N=3072 GEMM (WqT/WkT/WvT are contiguous in ws -> [3072][1024] bf16).
// k_attn is verbatim R6. v_cvt_pk_bf16_f32 is BANNED (R5/R8 both failed with
// it; R6/R4 without it passed — unbounded output => bad packed high half).

typedef unsigned short u16;
typedef __attribute__((ext_vector_type(8))) short short8;   // 8 x bf16
typedef __attribute__((ext_vector_type(4))) float f32x4;
typedef __attribute__((ext_vector_type(4))) unsigned short us4;

#define AS1 __attribute__((address_space(1)))
#define AS3 __attribute__((address_space(3)))

#if __has_builtin(__builtin_amdgcn_exp2f)
#define EXP2(x) __builtin_amdgcn_exp2f(x)
#else
#define EXP2(x) exp2f(x)
#endif

__device__ __forceinline__ u16 f2bf(float x) {
    union { float f; uint32_t u; } c; c.f = x;
    uint32_t r = c.u + 0x7fffu + ((c.u >> 16) & 1u);   // RNE
    return (u16)(r >> 16);
}

__device__ __forceinline__ float bf2f(u16 x) {
    union { uint32_t u; float f; } c; c.u = (uint32_t)x << 16;
    return c.f;
}

__device__ __forceinline__ short8 ld8(const u16* p) { return *(const short8*)p; }

__device__ __forceinline__ void gld_lds16(const u16* g, u16* l) {
    __builtin_amdgcn_global_load_lds((const AS1 void*)g, (AS3 void*)l, 16, 0, 0);
}

// ---------------- convert f32 -> bf16 (vectorized x4) ----------------
__global__ void k_convert(const float* __restrict__ in, u16* __restrict__ out, int n4) {
    int i = blockIdx.x * blockDim.x + threadIdx.x;
    if (i >= n4) return;
    float4 v = *((const float4*)in + i);
    us4 o = { f2bf(v.x), f2bf(v.y), f2bf(v.z), f2bf(v.w) };
    *((us4*)out + i) = o;
}

// ---------------- transpose 4 weights, f32[K][N] -> bf16[N][K] ----------------
__global__ void k_transpose4(const float* __restrict__ W0, const float* __restrict__ W1,
                             const float* __restrict__ W2, const float* __restrict__ W3,
                             u16* __restrict__ T0, u16* __restrict__ T1,
                             u16* __restrict__ T2, u16* __restrict__ T3) {
    const float* W; u16* T;
    switch (blockIdx.z) {
        case 0: W = W0; T = T0; break;
        case 1: W = W1; T = T1; break;
        case 2: W = W2; T = T2; break;
        default: W = W3; T = T3; break;
    }
    __shared__ float tile[32][33];
    int n0 = blockIdx.x * 32, k0 = blockIdx.y * 32;
    int tx = threadIdx.x, ty = threadIdx.y;   // block (32,8)
    #pragma unroll
    for (int j = 0; j < 32; j += 8)
        tile[ty + j][tx] = W[(size_t)(k0 + ty + j) * 1024 + n0 + tx];
    __syncthreads();
    #pragma unroll
    for (int j = 0; j < 32; j += 8)
        T[(size_t)(n0 + ty + j) * 1024 + k0 + tx] = f2bf(tile[tx][ty + j]);
}

// ---------------- merged QKV GEMM ----------------
// C[8192x3072] = Xb[8192x1024] * Wt3[3072x1024]^T, grid (64, 24).
// Wt3 rows: [0,1024)=WqT, [1024,2048)=WkT, [2048,3072)=WvT (contiguous in ws).
// Per-block n0 spans one z only (1024 % 128 == 0). Output routing:
// z=0 -> Qb [B,H,S,d], z=1 -> Kb [B,H,S,d], z=2 -> Vt [B,H,d,S].
__global__ __launch_bounds__(256)
void k_gemm_qkv(const u16* __restrict__ A, const u16* __restrict__ Wt3,
                u16* __restrict__ Qb, u16* __restrict__ Kb, u16* __restrict__ Vtw) {
    __shared__ u16 lA[128 * 64];
    __shared__ u16 lB[128 * 64];
    const int lane = threadIdx.x & 63, wave = threadIdx.x >> 6;
    const int lo = lane & 15, hi = lane >> 4;
    const int m0 = blockIdx.x * 128, n0 = blockIdx.y * 128;
    const int z = n0 >> 10;                      // block-uniform
    const u16* outb = (z == 0) ? Qb : (z == 1) ? Kb : Vtw;  // silence unused warn path
    const int wr = wave >> 1, wc = wave & 1;
    const int srow = lane >> 3;
    const int scol = (lane & 7) * 8;

    f32x4 acc[4][4];
    #pragma unroll
    for (int mi = 0; mi < 4; mi++)
        #pragma unroll
        for (int ni = 0; ni < 4; ni++)
            acc[mi][ni] = f32x4{0.f, 0.f, 0.f, 0.f};

    for (int k0 = 0; k0 < 1024; k0 += 64) {
        __syncthreads();
        #pragma unroll
        for (int i = 0; i < 4; i++) {
            int c = i * 4 + wave;
            int r = c * 8 + srow;
            gld_lds16(A   + (size_t)(m0 + r) * 1024 + k0 + scol, lA + c * 512);
            gld_lds16(Wt3 + (size_t)(n0 + r) * 1024 + k0 + scol, lB + c * 512);
        }
        __syncthreads();
        #pragma unroll
        for (int kk = 0; kk < 2; kk++) {
            short8 af[4], bf[4];
            #pragma unroll
            for (int mi = 0; mi < 4; mi++)
                af[mi] = ld8(lA + (wr * 64 + mi * 16 + lo) * 64 + kk * 32 + hi * 8);
            #pragma unroll
            for (int ni = 0; ni < 4; ni++)
                bf[ni] = ld8(lB + (wc * 64 + ni * 16 + lo) * 64 + kk * 32 + hi * 8);
            #pragma unroll
            for (int mi = 0; mi < 4; mi++)
                #pragma unroll
                for (int ni = 0; ni < 4; ni++)
                    acc[mi][ni] = __builtin_amdgcn_mfma_f32_16x16x32_bf16(
                        af[mi], bf[ni], acc[mi][ni], 0, 0, 0);
        }
    }

    u16* ob = const_cast<u16*>(outb);
    #pragma unroll
    for (int mi = 0; mi < 4; mi++) {
        #pragma unroll
        for (int ni = 0; ni < 4; ni++) {
            #pragma unroll
            for (int r = 0; r < 4; r++) {
                int row = m0 + wr * 64 + mi * 16 + hi * 4 + r;
                int col = (n0 & 1023) + wc * 64 + ni * 16 + lo;   // within this z
                float v = acc[mi][ni][r];
                int b = row >> 11, s = row & 2047, h = col >> 6, dh = col & 63;
                if (z < 2)
                    ob[((size_t)(b * 16 + h) * 2048 + s) * 64 + dh] = f2bf(v);
                else
                    ob[((size_t)(b * 16 + h) * 64 + dh) * 2048 + s] = f2bf(v);
            }
        }
    }
}

// ---------------- output GEMM: f32 out + bias ----------------
__global__ __launch_bounds__(256)
void k_gemm_out(const u16* __restrict__ A, const u16* __restrict__ Bt,
                float* __restrict__ outf, const float* __restrict__ bias) {
    __shared__ u16 lA[128 * 64];
    __shared__ u16 lB[128 * 64];
    const int lane = threadIdx.x & 63, wave = threadIdx.x >> 6;
    const int lo = lane & 15, hi = lane >> 4;
    const int m0 = blockIdx.x * 128, n0 = blockIdx.y * 128;
    const int wr = wave >> 1, wc = wave & 1;
    const int srow = lane >> 3;
    const int scol = (lane & 7) * 8;

    f32x4 acc[4][4];
    #pragma unroll
    for (int mi = 0; mi < 4; mi++)
        #pragma unroll
        for (int ni = 0; ni < 4; ni++)
            acc[mi][ni] = f32x4{0.f, 0.f, 0.f, 0.f};

    for (int k0 = 0; k0 < 1024; k0 += 64) {
        __syncthreads();
        #pragma unroll
        for (int i = 0; i < 4; i++) {
            int c = i * 4 + wave;
            int r = c * 8 + srow;
            gld_lds16(A  + (size_t)(m0 + r) * 1024 + k0 + scol, lA + c * 512);
            gld_lds16(Bt + (size_t)(n0 + r) * 1024 + k0 + scol, lB + c * 512);
        }
        __syncthreads();
        #pragma unroll
        for (int kk = 0; kk < 2; kk++) {
            short8 af[4], bf[4];
            #pragma unroll
            for (int mi = 0; mi < 4; mi++)
                af[mi] = ld8(lA + (wr * 64 + mi * 16 + lo) * 64 + kk * 32 + hi * 8);
            #pragma unroll
            for (int ni = 0; ni < 4; ni++)
                bf[ni] = ld8(lB + (wc * 64 + ni * 16 + lo) * 64 + kk * 32 + hi * 8);
            #pragma unroll
            for (int mi = 0; mi < 4; mi++)
                #pragma unroll
                for (int ni = 0; ni < 4; ni++)
                    acc[mi][ni] = __builtin_amdgcn_mfma_f32_16x16x32_bf16(
                        af[mi], bf[ni], acc[mi][ni], 0, 0, 0);
        }
    }

    #pragma unroll
    for (int mi = 0; mi < 4; mi++) {
        #pragma unroll
        for (int ni = 0; ni < 4; ni++) {
            #pragma unroll
            for (int r = 0; r < 4; r++) {
                int row = m0 + wr * 64 + mi * 16 + hi * 4 + r;
                int col = n0 + wc * 64 + ni * 16 + lo;
                outf[(size_t)row * 1024 + col] = acc[mi][ni][r] + bias[col];
            }
        }
    }
}

// ---------------- flash attention (swapped QK^T, verbatim R6) ----------------
// grid (bh=64, qt=8), block 512 (8 waves x 32 q-rows).
// sc = mfma(kf, qf): lane owns S[q=lane&15][kv=ct*16+hi*4+r] -> in-lane softmax,
// f2bf packing (bf16-round BEFORE sum so num/den correlate), shfl redistribution.
__global__ __launch_bounds__(512)
void k_attn(const u16* __restrict__ Q, const u16* __restrict__ K,
            const u16* __restrict__ Vt, u16* __restrict__ O) {
    const int lane = threadIdx.x & 63, wave = threadIdx.x >> 6;   // 8 waves
    const int lo = lane & 15, hi = lane >> 4;
    const int bh = blockIdx.x, qt = blockIdx.y;
    const u16* q  = Q  + (size_t)bh * (2048 * 64);
    const u16* k  = K  + (size_t)bh * (2048 * 64);
    const u16* vt = Vt + (size_t)bh * (64 * 2048);

    __shared__ u16 lK[2][64 * 64];   // [kv][d], swizzled: byte = row*128 + (bc ^ ((row&7)<<4))
    __shared__ u16 lV[2][64 * 64];   // [d][kv], same swizzle
    __shared__ u16 Pl[8][16 * 64];   // per-wave P [q][kv] bf16, swizzle ^((q&7)<<4)
    char* pwc = (char*)Pl[wave];

    const int q0 = qt * 256 + wave * 32;
    const float SL = 0.18033688011112042f;   // 0.125 * log2(e)
    const int swzlo = (lo & 7) << 4;

    // staging: linear LDS dest, inverse-swizzled global source
    const int srow = (wave << 3) + (lane >> 3);
    const int ssw  = ((lane & 7) ^ (srow & 7)) << 3;
    const u16* kbase = k  + (size_t)srow * 64   + ssw;
    const u16* vbase = vt + (size_t)srow * 2048 + ssw;

    // Q fragments (col=q=lo, k=d=hi*8+j)
    short8 qf[2][2];
    #pragma unroll
    for (int s = 0; s < 2; s++)
        #pragma unroll
        for (int kk = 0; kk < 2; kk++)
            qf[s][kk] = ld8(q + (size_t)(q0 + s * 16 + lo) * 64 + kk * 32 + hi * 8);

    f32x4 acc[2][4];   // acc[s][dt][r] = O[q=hi*4+r][d=dt*16+lo]
    #pragma unroll
    for (int s = 0; s < 2; s++)
        #pragma unroll
        for (int dt = 0; dt < 4; dt++) acc[s][dt] = f32x4{0.f, 0.f, 0.f, 0.f};
    float m2[2] = { -1e30f, -1e30f };   // per-lane (q = lo), SL-domain
    float lp[2] = { 0.f, 0.f };         // per-lane partial denominators

    gld_lds16(kbase, lK[0] + (wave << 9));
    gld_lds16(vbase, lV[0] + (wave << 9));
    __syncthreads();

    int cur = 0;
    for (int t = 0; t < 32; t++) {
        if (t + 1 < 32) {
            int kv = (t + 1) << 6;
            gld_lds16(kbase + (size_t)kv * 64, lK[cur ^ 1] + (wave << 9));
            gld_lds16(vbase + kv,              lV[cur ^ 1] + (wave << 9));
        }
        const char* Kc = (const char*)lK[cur];
        const char* Vc = (const char*)lV[cur];

        #pragma unroll
        for (int s = 0; s < 2; s++) {
            // ---- S^T = mfma(K, Q): sc[ct][r] = S[q=lo][kv=ct*16+hi*4+r] ----
            f32x4 sc[4];
            #pragma unroll
            for (int ct = 0; ct < 4; ct++) sc[ct] = f32x4{0.f, 0.f, 0.f, 0.f};
            #pragma unroll
            for (int kk = 0; kk < 2; kk++) {
                #pragma unroll
                for (int ct = 0; ct < 4; ct++) {
                    int row = ct * 16 + lo;
                    short8 kf = *(const short8*)(Kc + row * 128 +
                        (((kk << 6) + (hi << 4)) ^ ((row & 7) << 4)));
                    sc[ct] = __builtin_amdgcn_mfma_f32_16x16x32_bf16(kf, qf[s][kk], sc[ct], 0, 0, 0);
                }
            }
            // ---- per-lane online softmax (q = lo) ----
            float mA = fmaxf(fmaxf(sc[0][0], sc[0][1]), fmaxf(sc[0][2], sc[0][3]));
            float mB = fmaxf(fmaxf(sc[1][0], sc[1][1]), fmaxf(sc[1][2], sc[1][3]));
            float mC = fmaxf(fmaxf(sc[2][0], sc[2][1]), fmaxf(sc[2][2], sc[2][3]));
            float mD = fmaxf(fmaxf(sc[3][0], sc[3][1]), fmaxf(sc[3][2], sc[3][3]));
            float mx = fmaxf(fmaxf(mA, mB), fmaxf(mC, mD));
            mx = fmaxf(mx, __shfl_xor(mx, 16));
            mx = fmaxf(mx, __shfl_xor(mx, 32));
            float mn = fmaxf(m2[s], mx * SL);
            float al = EXP2(m2[s] - mn);
            m2[s] = mn;
            // ---- P = exp2(S*SL - mn), bf16-round before sum; write P LDS ----
            float sum = 0.f;
            #pragma unroll
            for (int ct = 0; ct < 4; ct++) {
                #pragma unroll
                for (int wp = 0; wp < 2; wp++) {
                    float e0 = EXP2(sc[ct][2 * wp]     * SL - mn);
                    float e1 = EXP2(sc[ct][2 * wp + 1] * SL - mn);
                    uint32_t b0 = f2bf(e0), b1 = f2bf(e1);
                    sum += bf2f((u16)b0) + bf2f((u16)b1);
                    *(uint32_t*)(pwc +
                        ((lo * 128 + (ct << 5) + (hi << 3) + (wp << 2)) ^ swzlo)) =
                        b0 | (b1 << 16);
                }
            }
            lp[s] = lp[s] * al + sum;
            asm volatile("" ::: "memory");   // order P stores before P loads
            // ---- rescale acc: al lives at q=lo; acc rows are q=hi*4+r ----
            float alr[4];
            #pragma unroll
            for (int r = 0; r < 4; r++) alr[r] = __shfl(al, (hi << 2) + r);
            #pragma unroll
            for (int dt = 0; dt < 4; dt++)
                #pragma unroll
                for (int r = 0; r < 4; r++) acc[s][dt][r] *= alr[r];
            // ---- O += P V ----
            #pragma unroll
            for (int nb = 0; nb < 2; nb++) {
                int prow = lo;
                short8 pa = *(const short8*)(pwc +
                    ((prow * 128 + ((nb << 6) + (hi << 4))) ^ ((prow & 7) << 4)));
                #pragma unroll
                for (int dt = 0; dt < 4; dt++) {
                    int vrow = dt * 16 + lo;
                    short8 vf = *(const short8*)(Vc + vrow * 128 +
                        (((nb << 6) + (hi << 4)) ^ ((vrow & 7) << 4)));
                    acc[s][dt] = __builtin_amdgcn_mfma_f32_16x16x32_bf16(pa, vf, acc[s][dt], 0, 0, 0);
                }
            }
            asm volatile("" ::: "memory");   // order P loads before next-phase stores
        }
        __syncthreads();   // drains prefetch vmcnt; protects K/V buffer swap
        cur ^= 1;
    }

    // ---- final denominator + write [B,S,H*d] bf16 ----
    const int b = bh >> 4, h = bh & 15;
    #pragma unroll
    for (int s = 0; s < 2; s++) {
        float l = lp[s];
        l += __shfl_xor(l, 16);
        l += __shfl_xor(l, 32);
        float ln[4];
        #pragma unroll
        for (int r = 0; r < 4; r++) ln[r] = 1.0f / __shfl(l, (hi << 2) + r);
        #pragma unroll
        for (int dt = 0; dt < 4; dt++) {
            #pragma unroll
            for (int r = 0; r < 4; r++) {
                float o = acc[s][dt][r] * ln[r];
                int rowg = q0 + s * 16 + (hi << 2) + r;
                int col  = dt * 16 + lo;
                O[((size_t)(b * 2048 + rowg)) * 1024 + h * 64 + col] = f2bf(o);
            }
        }
    }
}

// ---------------- launcher ----------------
extern "C" void kernel_launch(void* const* d_in, const int* in_sizes, int n_in,
                              void* d_out, int out_size, void* d_ws, size_t ws_size,
                              hipStream_t stream) {
    const float* X  = (const float*)d_in[0];
    const float* Wq = (const float*)d_in[1];
    const float* Wk = (const float*)d_in[2];
    const float* Wv = (const float*)d_in[3];
    const float* Wo = (const float*)d_in[4];
    const float* bo = (const float*)d_in[5];
    float* out = (float*)d_out;
    char* ws = (char*)d_ws;
    const size_t MB = 1024 * 1024;
    u16* Xb  = (u16*)(ws + 0 * MB);
    u16* WqT = (u16*)(ws + 16 * MB);   // [16,22) MB = contiguous [3072][1024] bf16
    u16* WkT = (u16*)(ws + 18 * MB);
    u16* WvT = (u16*)(ws + 20 * MB);
    u16* WoT = (u16*)(ws + 22 * MB);
    u16* Qb  = (u16*)(ws + 24 * MB);
    u16* Kb  = (u16*)(ws + 40 * MB);
    u16* Vt  = (u16*)(ws + 56 * MB);
    u16* Ab  = (u16*)(ws + 72 * MB);

    k_convert<<<8192, 256, 0, stream>>>(X, Xb, 8192 * 1024 / 4);
    k_transpose4<<<dim3(32, 32, 4), dim3(32, 8), 0, stream>>>(Wq, Wk, Wv, Wo, WqT, WkT, WvT, WoT);
    k_gemm_qkv<<<dim3(64, 24), 256, 0, stream>>>(Xb, WqT, Qb, Kb, Vt);
    k_attn<<<dim3(64, 8), 512, 0, stream>>>(Qb, Kb, Vt, Ab);
    k_gemm_out<<<dim3(64, 8), 256, 0, stream>>>(Ab, WoT, out, bo);
}

// Round 11
// 312.915 us; speedup vs baseline: 2.8531x; 1.0601x over previous
//
#include <hip/hip_runtime.h>
#include <hip/hip_bf16.h>
#include <stdint.h>

// CrossAttention forward, MI355X/gfx950.
// R11 = R10 resubmitted verbatim (R10 bench was a GPU-acquisition timeout).
// R10 = R9 (verified, 331.7us) with TWO low-risk changes:
//  (1) k_gemm_qkv z==2 epilogue: V^T stores packed 4x s-contiguous -> us4 8B
//      (was 64 scalar 2B stores at 4KB stride = ~32x write amplification).
//  (2) k_attn: defer-max (T13) — skip al/rescale/m2-update when
//      __all(mx*SL <= m2+3) (wave-uniform). P bounded by 8, bf16-safe.
// v_cvt_pk_bf16_f32 remains BANNED (R5/R8 failures).

typedef unsigned short u16;
typedef __attribute__((ext_vector_type(8))) short short8;   // 8 x bf16
typedef __attribute__((ext_vector_type(4))) float f32x4;
typedef __attribute__((ext_vector_type(4))) unsigned short us4;

#define AS1 __attribute__((address_space(1)))
#define AS3 __attribute__((address_space(3)))

#if __has_builtin(__builtin_amdgcn_exp2f)
#define EXP2(x) __builtin_amdgcn_exp2f(x)
#else
#define EXP2(x) exp2f(x)
#endif

__device__ __forceinline__ u16 f2bf(float x) {
    union { float f; uint32_t u; } c; c.f = x;
    uint32_t r = c.u + 0x7fffu + ((c.u >> 16) & 1u);   // RNE
    return (u16)(r >> 16);
}

__device__ __forceinline__ float bf2f(u16 x) {
    union { uint32_t u; float f; } c; c.u = (uint32_t)x << 16;
    return c.f;
}

__device__ __forceinline__ short8 ld8(const u16* p) { return *(const short8*)p; }

__device__ __forceinline__ void gld_lds16(const u16* g, u16* l) {
    __builtin_amdgcn_global_load_lds((const AS1 void*)g, (AS3 void*)l, 16, 0, 0);
}

// ---------------- convert f32 -> bf16 (vectorized x4) ----------------
__global__ void k_convert(const float* __restrict__ in, u16* __restrict__ out, int n4) {
    int i = blockIdx.x * blockDim.x + threadIdx.x;
    if (i >= n4) return;
    float4 v = *((const float4*)in + i);
    us4 o = { f2bf(v.x), f2bf(v.y), f2bf(v.z), f2bf(v.w) };
    *((us4*)out + i) = o;
}

// ---------------- transpose 4 weights, f32[K][N] -> bf16[N][K] ----------------
__global__ void k_transpose4(const float* __restrict__ W0, const float* __restrict__ W1,
                             const float* __restrict__ W2, const float* __restrict__ W3,
                             u16* __restrict__ T0, u16* __restrict__ T1,
                             u16* __restrict__ T2, u16* __restrict__ T3) {
    const float* W; u16* T;
    switch (blockIdx.z) {
        case 0: W = W0; T = T0; break;
        case 1: W = W1; T = T1; break;
        case 2: W = W2; T = T2; break;
        default: W = W3; T = T3; break;
    }
    __shared__ float tile[32][33];
    int n0 = blockIdx.x * 32, k0 = blockIdx.y * 32;
    int tx = threadIdx.x, ty = threadIdx.y;   // block (32,8)
    #pragma unroll
    for (int j = 0; j < 32; j += 8)
        tile[ty + j][tx] = W[(size_t)(k0 + ty + j) * 1024 + n0 + tx];
    __syncthreads();
    #pragma unroll
    for (int j = 0; j < 32; j += 8)
        T[(size_t)(n0 + ty + j) * 1024 + k0 + tx] = f2bf(tile[tx][ty + j]);
}

// ---------------- merged QKV GEMM ----------------
// C[8192x3072] = Xb[8192x1024] * Wt3[3072x1024]^T, grid (64, 24).
// z = n0>>10: z=0 -> Qb [B,H,S,d], z=1 -> Kb [B,H,S,d], z=2 -> Vt [B,H,d,S].
__global__ __launch_bounds__(256)
void k_gemm_qkv(const u16* __restrict__ A, const u16* __restrict__ Wt3,
                u16* __restrict__ Qb, u16* __restrict__ Kb, u16* __restrict__ Vtw) {
    __shared__ u16 lA[128 * 64];
    __shared__ u16 lB[128 * 64];
    const int lane = threadIdx.x & 63, wave = threadIdx.x >> 6;
    const int lo = lane & 15, hi = lane >> 4;
    const int m0 = blockIdx.x * 128, n0 = blockIdx.y * 128;
    const int z = n0 >> 10;                      // block-uniform
    const int wr = wave >> 1, wc = wave & 1;
    const int srow = lane >> 3;
    const int scol = (lane & 7) * 8;

    f32x4 acc[4][4];
    #pragma unroll
    for (int mi = 0; mi < 4; mi++)
        #pragma unroll
        for (int ni = 0; ni < 4; ni++)
            acc[mi][ni] = f32x4{0.f, 0.f, 0.f, 0.f};

    for (int k0 = 0; k0 < 1024; k0 += 64) {
        __syncthreads();
        #pragma unroll
        for (int i = 0; i < 4; i++) {
            int c = i * 4 + wave;
            int r = c * 8 + srow;
            gld_lds16(A   + (size_t)(m0 + r) * 1024 + k0 + scol, lA + c * 512);
            gld_lds16(Wt3 + (size_t)(n0 + r) * 1024 + k0 + scol, lB + c * 512);
        }
        __syncthreads();
        #pragma unroll
        for (int kk = 0; kk < 2; kk++) {
            short8 af[4], bf[4];
            #pragma unroll
            for (int mi = 0; mi < 4; mi++)
                af[mi] = ld8(lA + (wr * 64 + mi * 16 + lo) * 64 + kk * 32 + hi * 8);
            #pragma unroll
            for (int ni = 0; ni < 4; ni++)
                bf[ni] = ld8(lB + (wc * 64 + ni * 16 + lo) * 64 + kk * 32 + hi * 8);
            #pragma unroll
            for (int mi = 0; mi < 4; mi++)
                #pragma unroll
                for (int ni = 0; ni < 4; ni++)
                    acc[mi][ni] = __builtin_amdgcn_mfma_f32_16x16x32_bf16(
                        af[mi], bf[ni], acc[mi][ni], 0, 0, 0);
        }
    }

    if (z < 2) {
        u16* ob = (z == 0) ? Qb : Kb;
        #pragma unroll
        for (int mi = 0; mi < 4; mi++) {
            #pragma unroll
            for (int ni = 0; ni < 4; ni++) {
                #pragma unroll
                for (int r = 0; r < 4; r++) {
                    int row = m0 + wr * 64 + mi * 16 + hi * 4 + r;
                    int col = (n0 & 1023) + wc * 64 + ni * 16 + lo;
                    int b = row >> 11, s = row & 2047, h = col >> 6, dh = col & 63;
                    ob[((size_t)(b * 16 + h) * 2048 + s) * 64 + dh] = f2bf(acc[mi][ni][r]);
                }
            }
        }
    } else {
        // V^T: the 4 r-regs are s-contiguous (row0 % 4 == 0, can't cross a
        // 2048 boundary) -> pack into one 8B us4 store per (mi,ni).
        #pragma unroll
        for (int mi = 0; mi < 4; mi++) {
            #pragma unroll
            for (int ni = 0; ni < 4; ni++) {
                int row0 = m0 + wr * 64 + mi * 16 + hi * 4;
                int col  = (n0 & 1023) + wc * 64 + ni * 16 + lo;
                int b = row0 >> 11, s = row0 & 2047, h = col >> 6, dh = col & 63;
                us4 pk = { f2bf(acc[mi][ni][0]), f2bf(acc[mi][ni][1]),
                           f2bf(acc[mi][ni][2]), f2bf(acc[mi][ni][3]) };
                *(us4*)(Vtw + ((size_t)(b * 16 + h) * 64 + dh) * 2048 + s) = pk;
            }
        }
    }
}

// ---------------- output GEMM: f32 out + bias ----------------
__global__ __launch_bounds__(256)
void k_gemm_out(const u16* __restrict__ A, const u16* __restrict__ Bt,
                float* __restrict__ outf, const float* __restrict__ bias) {
    __shared__ u16 lA[128 * 64];
    __shared__ u16 lB[128 * 64];
    const int lane = threadIdx.x & 63, wave = threadIdx.x >> 6;
    const int lo = lane & 15, hi = lane >> 4;
    const int m0 = blockIdx.x * 128, n0 = blockIdx.y * 128;
    const int wr = wave >> 1, wc = wave & 1;
    const int srow = lane >> 3;
    const int scol = (lane & 7) * 8;

    f32x4 acc[4][4];
    #pragma unroll
    for (int mi = 0; mi < 4; mi++)
        #pragma unroll
        for (int ni = 0; ni < 4; ni++)
            acc[mi][ni] = f32x4{0.f, 0.f, 0.f, 0.f};

    for (int k0 = 0; k0 < 1024; k0 += 64) {
        __syncthreads();
        #pragma unroll
        for (int i = 0; i < 4; i++) {
            int c = i * 4 + wave;
            int r = c * 8 + srow;
            gld_lds16(A  + (size_t)(m0 + r) * 1024 + k0 + scol, lA + c * 512);
            gld_lds16(Bt + (size_t)(n0 + r) * 1024 + k0 + scol, lB + c * 512);
        }
        __syncthreads();
        #pragma unroll
        for (int kk = 0; kk < 2; kk++) {
            short8 af[4], bf[4];
            #pragma unroll
            for (int mi = 0; mi < 4; mi++)
                af[mi] = ld8(lA + (wr * 64 + mi * 16 + lo) * 64 + kk * 32 + hi * 8);
            #pragma unroll
            for (int ni = 0; ni < 4; ni++)
                bf[ni] = ld8(lB + (wc * 64 + ni * 16 + lo) * 64 + kk * 32 + hi * 8);
            #pragma unroll
            for (int mi = 0; mi < 4; mi++)
                #pragma unroll
                for (int ni = 0; ni < 4; ni++)
                    acc[mi][ni] = __builtin_amdgcn_mfma_f32_16x16x32_bf16(
                        af[mi], bf[ni], acc[mi][ni], 0, 0, 0);
        }
    }

    #pragma unroll
    for (int mi = 0; mi < 4; mi++) {
        #pragma unroll
        for (int ni = 0; ni < 4; ni++) {
            #pragma unroll
            for (int r = 0; r < 4; r++) {
                int row = m0 + wr * 64 + mi * 16 + hi * 4 + r;
                int col = n0 + wc * 64 + ni * 16 + lo;
                outf[(size_t)row * 1024 + col] = acc[mi][ni][r] + bias[col];
            }
        }
    }
}

// ---------------- flash attention (swapped QK^T + defer-max) ----------------
// grid (bh=64, qt=8), block 512 (8 waves x 32 q-rows).
// sc = mfma(kf, qf): lane owns S[q=lane&15][kv=ct*16+hi*4+r] -> in-lane softmax.
// defer-max: when __all(mx*SL <= m2+3) keep m_old (al=1), skip the
// exp2/shfl/rescale. P bounded by 2^3; denominator algebra unchanged.
__global__ __launch_bounds__(512)
void k_attn(const u16* __restrict__ Q, const u16* __restrict__ K,
            const u16* __restrict__ Vt, u16* __restrict__ O) {
    const int lane = threadIdx.x & 63, wave = threadIdx.x >> 6;   // 8 waves
    const int lo = lane & 15, hi = lane >> 4;
    const int bh = blockIdx.x, qt = blockIdx.y;
    const u16* q  = Q  + (size_t)bh * (2048 * 64);
    const u16* k  = K  + (size_t)bh * (2048 * 64);
    const u16* vt = Vt + (size_t)bh * (64 * 2048);

    __shared__ u16 lK[2][64 * 64];   // [kv][d], swizzled: byte = row*128 + (bc ^ ((row&7)<<4))
    __shared__ u16 lV[2][64 * 64];   // [d][kv], same swizzle
    __shared__ u16 Pl[8][16 * 64];   // per-wave P [q][kv] bf16, swizzle ^((q&7)<<4)
    char* pwc = (char*)Pl[wave];

    const int q0 = qt * 256 + wave * 32;
    const float SL = 0.18033688011112042f;   // 0.125 * log2(e)
    const int swzlo = (lo & 7) << 4;

    // staging: linear LDS dest, inverse-swizzled global source
    const int srow = (wave << 3) + (lane >> 3);
    const int ssw  = ((lane & 7) ^ (srow & 7)) << 3;
    const u16* kbase = k  + (size_t)srow * 64   + ssw;
    const u16* vbase = vt + (size_t)srow * 2048 + ssw;

    // Q fragments (col=q=lo, k=d=hi*8+j)
    short8 qf[2][2];
    #pragma unroll
    for (int s = 0; s < 2; s++)
        #pragma unroll
        for (int kk = 0; kk < 2; kk++)
            qf[s][kk] = ld8(q + (size_t)(q0 + s * 16 + lo) * 64 + kk * 32 + hi * 8);

    f32x4 acc[2][4];   // acc[s][dt][r] = O[q=hi*4+r][d=dt*16+lo]
    #pragma unroll
    for (int s = 0; s < 2; s++)
        #pragma unroll
        for (int dt = 0; dt < 4; dt++) acc[s][dt] = f32x4{0.f, 0.f, 0.f, 0.f};
    float m2[2] = { -1e30f, -1e30f };   // per-lane (q = lo), SL-domain
    float lp[2] = { 0.f, 0.f };         // per-lane partial denominators

    gld_lds16(kbase, lK[0] + (wave << 9));
    gld_lds16(vbase, lV[0] + (wave << 9));
    __syncthreads();

    int cur = 0;
    for (int t = 0; t < 32; t++) {
        if (t + 1 < 32) {
            int kv = (t + 1) << 6;
            gld_lds16(kbase + (size_t)kv * 64, lK[cur ^ 1] + (wave << 9));
            gld_lds16(vbase + kv,              lV[cur ^ 1] + (wave << 9));
        }
        const char* Kc = (const char*)lK[cur];
        const char* Vc = (const char*)lV[cur];

        #pragma unroll
        for (int s = 0; s < 2; s++) {
            // ---- S^T = mfma(K, Q): sc[ct][r] = S[q=lo][kv=ct*16+hi*4+r] ----
            f32x4 sc[4];
            #pragma unroll
            for (int ct = 0; ct < 4; ct++) sc[ct] = f32x4{0.f, 0.f, 0.f, 0.f};
            #pragma unroll
            for (int kk = 0; kk < 2; kk++) {
                #pragma unroll
                for (int ct = 0; ct < 4; ct++) {
                    int row = ct * 16 + lo;
                    short8 kf = *(const short8*)(Kc + row * 128 +
                        (((kk << 6) + (hi << 4)) ^ ((row & 7) << 4)));
                    sc[ct] = __builtin_amdgcn_mfma_f32_16x16x32_bf16(kf, qf[s][kk], sc[ct], 0, 0, 0);
                }
            }
            // ---- per-lane online softmax (q = lo), defer-max ----
            float mA = fmaxf(fmaxf(sc[0][0], sc[0][1]), fmaxf(sc[0][2], sc[0][3]));
            float mB = fmaxf(fmaxf(sc[1][0], sc[1][1]), fmaxf(sc[1][2], sc[1][3]));
            float mC = fmaxf(fmaxf(sc[2][0], sc[2][1]), fmaxf(sc[2][2], sc[2][3]));
            float mD = fmaxf(fmaxf(sc[3][0], sc[3][1]), fmaxf(sc[3][2], sc[3][3]));
            float mx = fmaxf(fmaxf(mA, mB), fmaxf(mC, mD));
            mx = fmaxf(mx, __shfl_xor(mx, 16));
            mx = fmaxf(mx, __shfl_xor(mx, 32));
            float mxs = mx * SL;
            bool nogrow = __all(mxs <= m2[s] + 3.0f);   // wave-uniform
            float mn = m2[s], al = 1.0f;
            if (!nogrow) {
                mn = fmaxf(m2[s], mxs);
                al = EXP2(m2[s] - mn);
                m2[s] = mn;
            }
            // ---- P = exp2(S*SL - mn), bf16-round before sum; write P LDS ----
            float sum = 0.f;
            #pragma unroll
            for (int ct = 0; ct < 4; ct++) {
                #pragma unroll
                for (int wp = 0; wp < 2; wp++) {
                    float e0 = EXP2(sc[ct][2 * wp]     * SL - mn);
                    float e1 = EXP2(sc[ct][2 * wp + 1] * SL - mn);
                    uint32_t b0 = f2bf(e0), b1 = f2bf(e1);
                    sum += bf2f((u16)b0) + bf2f((u16)b1);
                    *(uint32_t*)(pwc +
                        ((lo * 128 + (ct << 5) + (hi << 3) + (wp << 2)) ^ swzlo)) =
                        b0 | (b1 << 16);
                }
            }
            asm volatile("" ::: "memory");   // order P stores before P loads
            if (nogrow) {
                lp[s] += sum;
            } else {
                lp[s] = lp[s] * al + sum;
                float alr[4];
                #pragma unroll
                for (int r = 0; r < 4; r++) alr[r] = __shfl(al, (hi << 2) + r);
                #pragma unroll
                for (int dt = 0; dt < 4; dt++)
                    #pragma unroll
                    for (int r = 0; r < 4; r++) acc[s][dt][r] *= alr[r];
            }
            // ---- O += P V ----
            #pragma unroll
            for (int nb = 0; nb < 2; nb++) {
                int prow = lo;
                short8 pa = *(const short8*)(pwc +
                    ((prow * 128 + ((nb << 6) + (hi << 4))) ^ ((prow & 7) << 4)));
                #pragma unroll
                for (int dt = 0; dt < 4; dt++) {
                    int vrow = dt * 16 + lo;
                    short8 vf = *(const short8*)(Vc + vrow * 128 +
                        (((nb << 6) + (hi << 4)) ^ ((vrow & 7) << 4)));
                    acc[s][dt] = __builtin_amdgcn_mfma_f32_16x16x32_bf16(pa, vf, acc[s][dt], 0, 0, 0);
                }
            }
            asm volatile("" ::: "memory");   // order P loads before next-phase stores
        }
        __syncthreads();   // drains prefetch vmcnt; protects K/V buffer swap
        cur ^= 1;
    }

    // ---- final denominator + write [B,S,H*d] bf16 ----
    const int b = bh >> 4, h = bh & 15;
    #pragma unroll
    for (int s = 0; s < 2; s++) {
        float l = lp[s];
        l += __shfl_xor(l, 16);
        l += __shfl_xor(l, 32);
        float ln[4];
        #pragma unroll
        for (int r = 0; r < 4; r++) ln[r] = 1.0f / __shfl(l, (hi << 2) + r);
        #pragma unroll
        for (int dt = 0; dt < 4; dt++) {
            #pragma unroll
            for (int r = 0; r < 4; r++) {
                float o = acc[s][dt][r] * ln[r];
                int rowg = q0 + s * 16 + (hi << 2) + r;
                int col  = dt * 16 + lo;
                O[((size_t)(b * 2048 + rowg)) * 1024 + h * 64 + col] = f2bf(o);
            }
        }
    }
}

// ---------------- launcher ----------------
extern "C" void kernel_launch(void* const* d_in, const int* in_sizes, int n_in,
                              void* d_out, int out_size, void* d_ws, size_t ws_size,
                              hipStream_t stream) {
    const float* X  = (const float*)d_in[0];
    const float* Wq = (const float*)d_in[1];
    const float* Wk = (const float*)d_in[2];
    const float* Wv = (const float*)d_in[3];
    const float* Wo = (const float*)d_in[4];
    const float* bo = (const float*)d_in[5];
    float* out = (float*)d_out;
    char* ws = (char*)d_ws;
    const size_t MB = 1024 * 1024;
    u16* Xb  = (u16*)(ws + 0 * MB);
    u16* WqT = (u16*)(ws + 16 * MB);   // [16,22) MB = contiguous [3072][1024] bf16
    u16* WkT = (u16*)(ws + 18 * MB);
    u16* WvT = (u16*)(ws + 20 * MB);
    u16* WoT = (u16*)(ws + 22 * MB);
    u16* Qb  = (u16*)(ws + 24 * MB);
    u16* Kb  = (u16*)(ws + 40 * MB);
    u16* Vt  = (u16*)(ws + 56 * MB);
    u16* Ab  = (u16*)(ws + 72 * MB);

    k_convert<<<8192, 256, 0, stream>>>(X, Xb, 8192 * 1024 / 4);
    k_transpose4<<<dim3(32, 32, 4), dim3(32, 8), 0, stream>>>(Wq, Wk, Wv, Wo, WqT, WkT, WvT, WoT);
    k_gemm_qkv<<<dim3(64, 24), 256, 0, stream>>>(Xb, WqT, Qb, Kb, Vt);
    k_attn<<<dim3(64, 8), 512, 0, stream>>>(Qb, Kb, Vt, Ab);
    k_gemm_out<<<dim3(64, 8), 256, 0, stream>>>(Ab, WoT, out, bo);
}